// Round 17
// baseline (356.191 us; speedup 1.0000x reference)
//
#include <hip/hip_runtime.h>
#include <math.h>

// FractalOpponent on MI355X, round 17.
// = R16 with the BARRIER REGION OVERLAP BUG fixed:
//   release lines live at (40+i)*16 = uint idx 640..1151, but region stride was
//   1024 -> release writes stomped the NEXT kernel's arrival counters (observed
//   as 8.7e6us valve timeouts in R16's profile). Region stride now 2048 uints.
//   Also: pred/dsteps read depth logits with agent-scope coherent loads.

#define H 2048
#define NB 512      // resident grid size for barrier kernels (2 blocks/CU)
#define PREP_NB 2048
typedef unsigned short u16;
typedef float f4v __attribute__((ext_vector_type(4)));

struct P {
  const float *x, *h0, *c0, *Wv, *Wo, *Wih, *Whh, *b_lstm, *router_w, *router_b,
              *expert_w, *expert_b, *dr_w, *dr_b, *ram_w, *ram_b, *ag_w, *ag_b;
  const u16 *bWv, *bWo, *bWhh, *bEx, *bRam, *bAg;
  float* out;
  float* ws;
};

// ---- ws layout (floats) ----
constexpr int CTRU   = 16384;    // 8 barrier regions x 2048 uints (no overlap)
constexpr int DL     = 16384;    // 3 x 4 floats (dl0, dl1, dl3)
constexpr int GT     = 16400;    // x@Wih accumulator, 8192
constexpr int NODE   = 24592;    // 5 x NODESZ
constexpr int NODESZ = 26624;
constexpr int THV = 0, ATT = 2048, GAC = 4096, EO = 12288, SO = 20480, CS = 22528, HP = 24576;
constexpr int FIN    = NODE + 5 * NODESZ;   // 157712
constexpr int FINSZ  = 8192;
constexpr int ANC = 0, GCC = 2048, HNo = 4096, AGGo = 6144;
constexpr int RH1 = FIN + 3 * FINSZ;        // 182288
constexpr int RF1 = RH1 + 2048;
constexpr int RC1 = RH1 + 4096;
constexpr int ZTOT = 5 * 20480 + 3 * 4096;
// bf16 mirror (element offsets): Wv 4M | Wo 4M | Whh 16M | Ex 16M | Ram 8M | Ag 8M
constexpr size_t BF_BYTE_OFF = 786432;      // 768KB > core ws end (~754KB)
constexpr size_t oWo  = 4194304;
constexpr size_t oWhh = 8388608;
constexpr size_t oEx  = 25165824;
constexpr size_t oRam = 41943040;
constexpr size_t oAg  = 50331648;
constexpr size_t BF_NODE = 41943040;
constexpr size_t BF_ALL  = 58720256;

__device__ __forceinline__ float sigm(float v) { return 1.f / (1.f + expf(-v)); }

__device__ __forceinline__ float coh_f(const float* p) {
  return __hip_atomic_load(p, __ATOMIC_RELAXED, __HIP_MEMORY_SCOPE_AGENT);
}
__device__ __forceinline__ void coh_st(float* p, float v) {
  __hip_atomic_store(p, v, __ATOMIC_RELAXED, __HIP_MEMORY_SCOPE_AGENT);
}

__device__ __forceinline__ float bfl(unsigned u) { union { unsigned x; float f; } c; c.x = u << 16; return c.f; }
__device__ __forceinline__ float bfh(unsigned u) { union { unsigned x; float f; } c; c.x = u & 0xFFFF0000u; return c.f; }
__device__ __forceinline__ u16 f2bf(float f) {
  unsigned u = __float_as_uint(f);
  u += 0x7FFFu + ((u >> 16) & 1u);
  return (u16)(u >> 16);
}

template <typename WT> struct W4;
template <> struct W4<float> {
  static __device__ __forceinline__ void load(const float* p, float* w) {
    const float4 v = *reinterpret_cast<const float4*>(p);
    w[0] = v.x; w[1] = v.y; w[2] = v.z; w[3] = v.w;
  }
};
template <> struct W4<u16> {
  static __device__ __forceinline__ void load(const u16* p, float* w) {
    const uint2 u = *reinterpret_cast<const uint2*>(p);
    w[0] = bfl(u.x); w[1] = bfh(u.x); w[2] = bfl(u.y); w[3] = bfh(u.y);
  }
};

template <typename WT> __device__ __forceinline__ const WT* selWv(const P& p);
template <> __device__ __forceinline__ const float* selWv<float>(const P& p) { return p.Wv; }
template <> __device__ __forceinline__ const u16*   selWv<u16>(const P& p)   { return p.bWv; }
template <typename WT> __device__ __forceinline__ const WT* selWo(const P& p);
template <> __device__ __forceinline__ const float* selWo<float>(const P& p) { return p.Wo; }
template <> __device__ __forceinline__ const u16*   selWo<u16>(const P& p)   { return p.bWo; }
template <typename WT> __device__ __forceinline__ const WT* selWhh(const P& p);
template <> __device__ __forceinline__ const float* selWhh<float>(const P& p) { return p.Whh; }
template <> __device__ __forceinline__ const u16*   selWhh<u16>(const P& p)   { return p.bWhh; }
template <typename WT> __device__ __forceinline__ const WT* selEx(const P& p);
template <> __device__ __forceinline__ const float* selEx<float>(const P& p) { return p.expert_w; }
template <> __device__ __forceinline__ const u16*   selEx<u16>(const P& p)   { return p.bEx; }
template <typename WT> __device__ __forceinline__ const WT* selRam(const P& p);
template <> __device__ __forceinline__ const float* selRam<float>(const P& p) { return p.ram_w; }
template <> __device__ __forceinline__ const u16*   selRam<u16>(const P& p)   { return p.bRam; }
template <typename WT> __device__ __forceinline__ const WT* selAg(const P& p);
template <> __device__ __forceinline__ const float* selAg<float>(const P& p) { return p.ag_w; }
template <> __device__ __forceinline__ const u16*   selAg<u16>(const P& p)   { return p.bAg; }

// Coherent depth-step read (dl written by combine via atomicAdd; read cross-kernel).
__device__ __forceinline__ int dsteps(const float* dla, const float* drb, int mx) {
  const float l0 = coh_f(dla + 0) + drb[0];
  const float l1 = coh_f(dla + 1) + drb[1];
  const float l2 = coh_f(dla + 2) + drb[2];
  int ch = 0; float bv = l0;
  if (l1 > bv) { bv = l1; ch = 1; }
  if (l2 > bv) { bv = l2; ch = 2; }
  return ch < mx ? ch : mx;
}

// pred codes: 0 always | 1 s0>=1 | 2 s0>=1&&s1>=1 | 3 s0>=2 | 4 s0>=2&&s3>=1
__device__ __forceinline__ bool pred(const float* ws, const float* drb, int code) {
  if (code == 0) return true;
  const int s0 = dsteps(ws + DL, drb, 2);
  switch (code) {
    case 1: return s0 >= 1;
    case 2: return s0 >= 1 && dsteps(ws + DL + 4, drb, 1) >= 1;
    case 3: return s0 >= 2;
    case 4: return s0 >= 2 && dsteps(ws + DL + 8, drb, 1) >= 1;
  }
  return true;
}

// Tree barrier, 512 blocks. Region = 2048 uints:
//   arrival line i (i<32) at [i*16]; master at [512]; release line i at [(40+i)*16]
//   (釋release max idx = 71*16+... = 1136..1151 < 2048: no overlap).
__device__ __forceinline__ void resbar(unsigned* ctr, int phase) {
  asm volatile("s_waitcnt vmcnt(0)" ::: "memory");
  __syncthreads();
  __shared__ int lastB;
  if (threadIdx.x == 0) {
    lastB = 0;
    unsigned* line = ctr + (blockIdx.x & 31) * 16;
    const unsigned prev = __hip_atomic_fetch_add(line, 1u, __ATOMIC_RELAXED, __HIP_MEMORY_SCOPE_AGENT);
    if (prev == (unsigned)(16 * phase) - 1u) {
      const unsigned m = __hip_atomic_fetch_add(ctr + 512, 1u, __ATOMIC_RELAXED, __HIP_MEMORY_SCOPE_AGENT);
      if (m == (unsigned)(32 * phase) - 1u) lastB = 1;
    }
  }
  __syncthreads();
  if (lastB) {
    if (threadIdx.x < 32)
      __hip_atomic_store(ctr + (40 + threadIdx.x) * 16, (unsigned)phase,
                         __ATOMIC_RELAXED, __HIP_MEMORY_SCOPE_AGENT);
  } else if (threadIdx.x == 0) {
    const unsigned* rel = ctr + (40 + (blockIdx.x & 31)) * 16;
    long t = 0;
    while (__hip_atomic_load(rel, __ATOMIC_RELAXED, __HIP_MEMORY_SCOPE_AGENT) < (unsigned)phase) {
      __builtin_amdgcn_s_sleep(2);
      if (++t > 30000000L) break;  // safety valve: fail absmax, not hang
    }
  }
  __syncthreads();
}

// Split-K GEMV phase, fully unrolled. y[j] += sum x[i]*W[i,j].
// XMODE: 0 plain concat(xA,xB @ splitPt) | 1 coherent xA | 2 concat(xA, xBias+coh xB)
template <int CHUNK, int XMODE, typename WT>
__device__ __forceinline__ void gemv_phase(
    int bid, int G,
    const float* xA, const float* xB, int splitPt, const float* xBias,
    const WT* __restrict__ W, float* __restrict__ y, int N,
    float* shx, float4* red)
{
  const int tid = threadIdx.x, lane = tid & 63, tsub = tid >> 6;
  const int g = bid % G, s = bid / G;
  const int base = s * CHUNK;
  for (int idx = tid; idx < CHUNK; idx += 256) {
    const int i = base + idx;
    float v;
    if (XMODE == 0)      v = (i < splitPt) ? xA[i] : xB[i - splitPt];
    else if (XMODE == 1) v = coh_f(xA + i);
    else                 v = (i < splitPt) ? xA[i] : (xBias[i - splitPt] + coh_f(xB + (i - splitPt)));
    shx[idx] = v;
  }
  __syncthreads();
  constexpr int LEN = CHUNK / 4;
  const int j = (g << 8) + (lane << 2);
  const WT* Wp = W + (size_t)(base + tsub * LEN) * N + j;
  float ax = 0.f, ay = 0.f, az = 0.f, aw = 0.f;
#pragma unroll
  for (int t = 0; t < LEN; ++t) {
    const float xi = shx[tsub * LEN + t];
    float w[4];
    W4<WT>::load(Wp + (size_t)t * N, w);
    ax = fmaf(xi, w[0], ax); ay = fmaf(xi, w[1], ay);
    az = fmaf(xi, w[2], az); aw = fmaf(xi, w[3], aw);
  }
  red[tid] = make_float4(ax, ay, az, aw);
  __syncthreads();
  if (tsub == 0) {
    float4 a = red[tid], b = red[tid + 64], c = red[tid + 128], d = red[tid + 192];
    atomicAdd(&y[j + 0], a.x + b.x + c.x + d.x);
    atomicAdd(&y[j + 1], a.y + b.y + c.y + d.y);
    atomicAdd(&y[j + 2], a.z + b.z + c.z + d.z);
    atomicAdd(&y[j + 3], a.w + b.w + c.w + d.w);
  }
}

// Expert GEMV + fused LSTM (32 col-groups x 16 K-slices of 128 rows).
template <typename WT>
__device__ void expert_phase(const P& p, float* nb, const float* c_in, const float* gt,
                             float* shx, float4* red)
{
  const int tid = threadIdx.x, lane = tid & 63, w = tid >> 6;
  const int g = blockIdx.x & 31, s = blockIdx.x >> 5;
  const int i0 = s * 128;
  if (tid < 128) {
    const int i = i0 + tid;
    const float gi = p.b_lstm[i]         + coh_f(gt + i)         + coh_f(nb + GAC + i);
    const float gf = p.b_lstm[H + i]     + coh_f(gt + H + i)     + coh_f(nb + GAC + H + i);
    const float gg = p.b_lstm[2 * H + i] + coh_f(gt + 2 * H + i) + coh_f(nb + GAC + 2 * H + i);
    const float go = p.b_lstm[3 * H + i] + coh_f(gt + 3 * H + i) + coh_f(nb + GAC + 3 * H + i);
    const float c2 = sigm(gf) * c_in[i] + sigm(gi) * tanhf(gg);
    const float h2 = sigm(go) * tanhf(c2);
    shx[tid] = h2;
    if (g == 0) { coh_st(nb + SO + i, h2); coh_st(nb + CS + i, c2); }
  }
  __syncthreads();
  const int j = (g << 8) + (lane << 2);
  const int e = j >> 11, k = j & (H - 1);
  const WT* Wp = selEx<WT>(p) + ((size_t)e << 22) + (size_t)(i0 + w * 32) * H + k;
  float ax = 0.f, ay = 0.f, az = 0.f, aw = 0.f;
#pragma unroll
  for (int t = 0; t < 32; ++t) {
    const float xi = shx[w * 32 + t];
    float wv[4];
    W4<WT>::load(Wp + (size_t)t * H, wv);
    ax = fmaf(xi, wv[0], ax); ay = fmaf(xi, wv[1], ay);
    az = fmaf(xi, wv[2], az); aw = fmaf(xi, wv[3], aw);
  }
  red[tid] = make_float4(ax, ay, az, aw);
  __syncthreads();
  if (w == 0) {
    float4 a = red[tid], b = red[tid + 64], c = red[tid + 128], d = red[tid + 192];
    atomicAdd(&nb[EO + j + 0], a.x + b.x + c.x + d.x);
    atomicAdd(&nb[EO + j + 1], a.y + b.y + c.y + d.y);
    atomicAdd(&nb[EO + j + 2], a.z + b.z + c.z + d.z);
    atomicAdd(&nb[EO + j + 3], a.w + b.w + c.w + d.w);
  }
}

// Combine phase: blocks 0..7, jj = bid*256+tid covers 2048.
__device__ void combine_phase(const P& p, float* nb, float* dla, int leaf, float damping,
                              const float* php, float* hn, float* agg, float4* red)
{
  const int tid = threadIdx.x;
  float r0 = 0.f, r1 = 0.f, r2 = 0.f, r3 = 0.f;
  for (int i = tid; i < H; i += 256) {
    const float hh = coh_f(nb + SO + i);
    const float4 rw = *reinterpret_cast<const float4*>(p.router_w + i * 4);
    r0 = fmaf(hh, rw.x, r0); r1 = fmaf(hh, rw.y, r1);
    r2 = fmaf(hh, rw.z, r2); r3 = fmaf(hh, rw.w, r3);
  }
  red[tid] = make_float4(r0, r1, r2, r3);
  __syncthreads();
  for (int off = 128; off > 0; off >>= 1) {
    if (tid < off) {
      const float4 b = red[tid + off];
      red[tid].x += b.x; red[tid].y += b.y; red[tid].z += b.z; red[tid].w += b.w;
    }
    __syncthreads();
  }
  const float4 L = red[0];
  __syncthreads();
  const float l0 = L.x + p.router_b[0], l1 = L.y + p.router_b[1];
  const float l2 = L.z + p.router_b[2], l3 = L.w + p.router_b[3];
  const float m = fmaxf(fmaxf(l0, l1), fmaxf(l2, l3));
  const float e0 = expf(l0 - m), e1 = expf(l1 - m), e2 = expf(l2 - m), e3 = expf(l3 - m);
  const float inv = 1.f / (e0 + e1 + e2 + e3);
  const float q0 = e0 * inv, q1 = e1 * inv, q2 = e2 * inv, q3 = e3 * inv;
  const int jj = blockIdx.x * 256 + tid;
  const float v = q0 * (p.expert_b[jj]         + coh_f(nb + EO + jj))
                + q1 * (p.expert_b[H + jj]     + coh_f(nb + EO + H + jj))
                + q2 * (p.expert_b[2 * H + jj] + coh_f(nb + EO + 2 * H + jj))
                + q3 * (p.expert_b[3 * H + jj] + coh_f(nb + EO + 3 * H + jj));
  if (leaf) {
    const float h0v = php[jj];
    const float hnv = h0v + damping * (v - h0v);
    hn[jj] = hnv;
    agg[jj] = h0v - 0.5f * hnv;
  } else {
    nb[HP + jj] = v;
    red[tid] = make_float4(v * p.dr_w[jj * 3 + 0], v * p.dr_w[jj * 3 + 1], v * p.dr_w[jj * 3 + 2], 0.f);
    __syncthreads();
    for (int off = 128; off > 0; off >>= 1) {
      if (tid < off) {
        const float4 b = red[tid + off];
        red[tid].x += b.x; red[tid].y += b.y; red[tid].z += b.z;
      }
      __syncthreads();
    }
    if (tid == 0) {
      atomicAdd(&dla[0], red[0].x);
      atomicAdd(&dla[1], red[0].y);
      atomicAdd(&dla[2], red[0].z);
    }
  }
}

// ---- tail phases (blocks 0..7) ----
__device__ void tail_fsel(const P& p, float* ws) {
  if (dsteps(ws + DL, p.dr_b, 2) < 1) return;
  const bool deep = dsteps(ws + DL + 4, p.dr_b, 1) >= 1;
  const int jj = blockIdx.x * 256 + threadIdx.x;
  const float* n1 = ws + NODE + 1 * NODESZ;
  const float* n2 = ws + NODE + 2 * NODESZ;
  const float* fb = ws + FIN;
  float rh, rf, rc;
  if (deep) {
    const float gacc = p.ag_b[jj] + coh_f(fb + GCC + jj);
    const float anc  = p.ram_b[jj] + coh_f(fb + ANC + jj);
    const float g = sigm(gacc);
    rh = g * anc + (1.f - g) * fb[HNo + jj];
    rf = n2[SO + jj]; rc = n2[CS + jj];
  } else {
    rh = n1[HP + jj]; rf = n1[SO + jj]; rc = n1[CS + jj];
  }
  ws[RH1 + jj] = rh; ws[RF1 + jj] = rf; ws[RC1 + jj] = rc;
}

__device__ void tail1(const P& p, float* ws) {
  const int s0 = dsteps(ws + DL, p.dr_b, 2);
  if (s0 < 1) return;
  const int jj = blockIdx.x * 256 + threadIdx.x;
  const float* n0 = ws + NODE;
  const float* n3 = ws + NODE + 3 * NODESZ;
  const float* n4 = ws + NODE + 4 * NODESZ;
  const float* fb3 = ws + FIN + FINSZ;
  float* fb0 = ws + FIN + 2 * FINSZ;
  const float r1 = ws[RH1 + jj];
  float rh3 = 0.f, rf3 = 0.f, rc3 = 0.f;
  if (s0 >= 2) {
    if (dsteps(ws + DL + 8, p.dr_b, 1) >= 1) {
      const float gacc = p.ag_b[jj] + coh_f(fb3 + GCC + jj);
      const float anc  = p.ram_b[jj] + coh_f(fb3 + ANC + jj);
      const float g = sigm(gacc);
      rh3 = g * anc + (1.f - g) * fb3[HNo + jj];
      rf3 = n4[SO + jj]; rc3 = n4[CS + jj];
    } else { rh3 = n3[HP + jj]; rf3 = n3[SO + jj]; rc3 = n3[CS + jj]; }
  }
  float ag = n0[HP + jj] - 0.5f * r1;
  float hc, oF, oC;
  if (s0 >= 2) { ag += (1.f / 3.f) * rh3; hc = rh3; oF = rf3; oC = rc3; }
  else { hc = r1; oF = ws[RF1 + jj]; oC = ws[RC1 + jj]; }
  fb0[AGGo + jj] = ag; fb0[HNo + jj] = hc;
  p.out[jj] = oF; p.out[2 * H + jj] = oC;
}

__device__ void tail2(const P& p, float* ws) {
  const int s0 = dsteps(ws + DL, p.dr_b, 2);
  const int jj = blockIdx.x * 256 + threadIdx.x;
  const float* n0 = ws + NODE;
  const float* fb0 = ws + FIN + 2 * FINSZ;
  if (s0 == 0) {
    p.out[jj] = n0[SO + jj]; p.out[H + jj] = n0[HP + jj]; p.out[2 * H + jj] = n0[CS + jj];
  } else {
    const float gacc = p.ag_b[jj] + coh_f(fb0 + GCC + jj);
    const float anc  = p.ram_b[jj] + coh_f(fb0 + ANC + jj);
    const float g = sigm(gacc);
    p.out[H + jj] = g * anc + (1.f - g) * fb0[HNo + jj];
  }
}

// ---- kernels ----
__global__ void __launch_bounds__(256) k_zero(P p) {
  float* ws = p.ws;
  const int gtid = blockIdx.x * 256 + threadIdx.x;
  const int gsz = gridDim.x * 256;
  unsigned* u = (unsigned*)ws;
  for (int i = gtid; i < CTRU; i += gsz) u[i] = 0u;
  if (gtid < 12) ws[DL + gtid] = 0.f;
  for (int i = gtid; i < 8192; i += gsz) ws[GT + i] = 0.f;
}

// High-occupancy prep (2048 blocks): zero accumulators + bf16 conversion with
// nontemporal fp32 reads + Wih GEMV spread over ALL blocks (G=32, KS=64).
__global__ void __launch_bounds__(256) k_prep(P p, u16* bf, int convMask) {
  float* ws = p.ws;
  __shared__ float shx[128];
  __shared__ float4 red[256];
  const size_t gtid = (size_t)blockIdx.x * 256 + threadIdx.x;
  const size_t nthr = (size_t)PREP_NB * 256;
  for (size_t i = gtid; i < (size_t)ZTOT; i += nthr) {
    if (i < 5 * 20480) {
      const int n = (int)(i / 20480), off = (int)(i % 20480);
      ws[NODE + n * NODESZ + off] = 0.f;
    } else {
      const int j = (int)(i - 5 * 20480);
      ws[FIN + (j >> 12) * FINSZ + (j & 4095)] = 0.f;
    }
  }
  auto conv = [&](const float* __restrict__ src, u16* __restrict__ dst, size_t elems) {
    for (size_t c = gtid; c < elems / 8; c += nthr) {
      const size_t e = c * 8;
      const f4v a = __builtin_nontemporal_load(reinterpret_cast<const f4v*>(src + e));
      const f4v b = __builtin_nontemporal_load(reinterpret_cast<const f4v*>(src + e + 4));
      uint4 o;
      o.x = (unsigned)f2bf(a.x) | ((unsigned)f2bf(a.y) << 16);
      o.y = (unsigned)f2bf(a.z) | ((unsigned)f2bf(a.w) << 16);
      o.z = (unsigned)f2bf(b.x) | ((unsigned)f2bf(b.y) << 16);
      o.w = (unsigned)f2bf(b.z) | ((unsigned)f2bf(b.w) << 16);
      *reinterpret_cast<uint4*>(dst + e) = o;
    }
  };
  if (convMask & 1) {
    conv(p.Wv,       bf,         oWo);
    conv(p.Wo,       bf + oWo,   oWhh - oWo);
    conv(p.Whh,      bf + oWhh,  oEx - oWhh);
    conv(p.expert_w, bf + oEx,   oRam - oEx);
  }
  if (convMask & 2) {
    conv(p.ram_w, bf + oRam, oAg - oRam);
    conv(p.ag_w,  bf + oAg,  BF_ALL - oAg);
  }
  gemv_phase<32, 0, float>(blockIdx.x, 32, p.x, p.x, 1 << 30, nullptr,
                           p.Wih, ws + GT, 4 * H, shx, red);
}

template <typename WT>
__global__ void __launch_bounds__(256, 2) k_node(
    P p, int nodeIdx, int ctrIdx, int predCode,
    const float* hv, const float* cv,
    int leaf, float damping, const float* php, float* hn, float* agg, float* dla)
{
  float* ws = p.ws;
  if (!pred(ws, p.dr_b, predCode)) return;
  __shared__ float shx[128];
  __shared__ float4 red[256];
  float* nb = ws + NODE + nodeIdx * NODESZ;
  unsigned* ctr = (unsigned*)ws + ctrIdx * 2048;
  gemv_phase<32, 0, WT>(blockIdx.x, 8, hv, hv, 1 << 30, nullptr, selWv<WT>(p), nb + THV, H, shx, red);
  resbar(ctr, 1);
  gemv_phase<32, 1, WT>(blockIdx.x, 8, nb + THV, nullptr, 0, nullptr, selWo<WT>(p), nb + ATT, H, shx, red);
  resbar(ctr, 2);
  gemv_phase<128, 1, WT>(blockIdx.x, 32, nb + ATT, nullptr, 0, nullptr, selWhh<WT>(p), nb + GAC, 4 * H, shx, red);
  resbar(ctr, 3);
  expert_phase<WT>(p, nb, cv, ws + GT, shx, red);
  resbar(ctr, 4);
  if (blockIdx.x >= 8) return;
  combine_phase(p, nb, dla, leaf, damping, php, hn, agg, red);
}

template <typename WT>
__global__ void __launch_bounds__(256, 2) k_fin(
    P p, int finIdx, int ctrIdx, int predCode,
    const float* aggv, const float* phpv, const float* hnv, int tailKind)
{
  float* ws = p.ws;
  __shared__ float shx[64];
  __shared__ float4 red[256];
  float* fb = ws + FIN + finIdx * FINSZ;
  unsigned* ctr = (unsigned*)ws + ctrIdx * 2048;
  const bool ok = pred(ws, p.dr_b, predCode);
  if (ok) {
    gemv_phase<64, 0, WT>(blockIdx.x, 8, aggv, phpv, H, nullptr, selRam<WT>(p), fb + ANC, H, shx, red);
    resbar(ctr, 1);
    gemv_phase<64, 2, WT>(blockIdx.x, 8, hnv, fb + ANC, H, p.ram_b, selAg<WT>(p), fb + GCC, H, shx, red);
    resbar(ctr, 2);
  }
  if (blockIdx.x >= 8) return;
  if (tailKind == 1) tail_fsel(p, ws);
  else if (tailKind == 2) tail1(p, ws);
  else tail2(p, ws);
}

extern "C" void kernel_launch(void* const* d_in, const int* in_sizes, int n_in,
                              void* d_out, int out_size, void* d_ws, size_t ws_size,
                              hipStream_t stream) {
  P p;
  p.x = (const float*)d_in[0];  p.h0 = (const float*)d_in[1];  p.c0 = (const float*)d_in[2];
  p.Wv = (const float*)d_in[5]; p.Wo = (const float*)d_in[6];
  p.Wih = (const float*)d_in[7]; p.Whh = (const float*)d_in[8];
  p.b_lstm = (const float*)d_in[9];
  p.router_w = (const float*)d_in[10]; p.router_b = (const float*)d_in[11];
  p.expert_w = (const float*)d_in[12]; p.expert_b = (const float*)d_in[13];
  p.dr_w = (const float*)d_in[14]; p.dr_b = (const float*)d_in[15];
  p.ram_w = (const float*)d_in[16]; p.ram_b = (const float*)d_in[17];
  p.ag_w = (const float*)d_in[18]; p.ag_b = (const float*)d_in[19];
  p.out = (float*)d_out;
  p.ws = (float*)d_ws;

  const bool useBf    = ws_size >= BF_BYTE_OFF + BF_NODE * 2 + 1024;
  const bool useBfFin = ws_size >= BF_BYTE_OFF + BF_ALL * 2 + 1024;
  u16* bf = (u16*)((char*)d_ws + BF_BYTE_OFF);
  p.bWv  = bf;        p.bWo = bf + oWo;  p.bWhh = bf + oWhh;
  p.bEx  = bf + oEx;  p.bRam = bf + oRam; p.bAg = bf + oAg;

  float* ws = p.ws;
  auto nb = [&](int n) { return ws + NODE + n * NODESZ; };
  float* fb1 = ws + FIN;
  float* fb3 = ws + FIN + FINSZ;
  float* fb0 = ws + FIN + 2 * FINSZ;

  auto node = [&](int n, int ctrIdx, int predCode, const float* hv, const float* cv,
                  int leaf, float damping, const float* php, float* hn, float* agg, float* dla) {
    if (useBf)
      k_node<u16><<<NB, 256, 0, stream>>>(p, n, ctrIdx, predCode, hv, cv, leaf, damping, php, hn, agg, dla);
    else
      k_node<float><<<NB, 256, 0, stream>>>(p, n, ctrIdx, predCode, hv, cv, leaf, damping, php, hn, agg, dla);
  };
  auto fin = [&](int f, int ctrIdx, int predCode, const float* aggv, const float* phpv,
                 const float* hnv, int tailKind) {
    if (useBfFin)
      k_fin<u16><<<NB, 256, 0, stream>>>(p, f, ctrIdx, predCode, aggv, phpv, hnv, tailKind);
    else
      k_fin<float><<<NB, 256, 0, stream>>>(p, f, ctrIdx, predCode, aggv, phpv, hnv, tailKind);
  };

  k_zero<<<16, 256, 0, stream>>>(p);
  k_prep<<<PREP_NB, 256, 0, stream>>>(p, bf, (useBf ? 1 : 0) | (useBfFin ? 2 : 0));
  // N0
  node(0, 0, 0, p.h0, p.c0, 0, 0.f, nullptr, nullptr, nullptr, ws + DL);
  // N1 (s0>=1)
  node(1, 1, 1, nb(0) + HP, nb(0) + CS, 0, 0.f, nullptr, nullptr, nullptr, ws + DL + 4);
  // N2 leaf (s0>=1 && s1>=1)
  node(2, 2, 2, nb(1) + HP, nb(1) + CS, 1, 0.25f, nb(1) + HP, fb1 + HNo, fb1 + AGGo, nullptr);
  // N1 finalize + fsel
  fin(0, 3, 2, fb1 + AGGo, nb(1) + HP, fb1 + HNo, 1);
  // N3 (s0>=2)
  node(3, 4, 3, ws + RH1, ws + RC1, 0, 0.f, nullptr, nullptr, nullptr, ws + DL + 8);
  // N4 leaf (s0>=2 && s3>=1)
  node(4, 5, 4, nb(3) + HP, nb(3) + CS, 1, 0.25f, nb(3) + HP, fb3 + HNo, fb3 + AGGo, nullptr);
  // N3 finalize + tail1
  fin(1, 6, 4, fb3 + AGGo, nb(3) + HP, fb3 + HNo, 2);
  // N0 finalize + tail2
  fin(2, 7, 1, fb0 + AGGo, nb(0) + HP, fb0 + HNo, 3);
}

// Round 18
// 345.667 us; speedup vs baseline: 1.0304x; 1.0304x over previous
//
#include <hip/hip_runtime.h>
#include <math.h>

// FractalOpponent on MI355X, round 18.
// = R17 with the standalone bf16-conversion pass ELIMINATED:
//   N0's GEMV phases read fp32 weights (nontemporal) and write the bf16 mirror
//   as a side effect (each block's tile is disjoint, full coverage); N1..N4 read
//   the mirror. fin1 converts ram_w/ag_w the same way (GEMVs run unconditionally
//   so the mirror exists even if fin1's pred is off; tails stay predicated).
//   k_prep is now just zeros + Wih GEMV.

#define H 2048
#define NB 512      // resident grid size for barrier kernels (2 blocks/CU)
#define PREP_NB 2048
typedef unsigned short u16;
typedef float f4v __attribute__((ext_vector_type(4)));

struct P {
  const float *x, *h0, *c0, *Wv, *Wo, *Wih, *Whh, *b_lstm, *router_w, *router_b,
              *expert_w, *expert_b, *dr_w, *dr_b, *ram_w, *ram_b, *ag_w, *ag_b;
  const u16 *bWv, *bWo, *bWhh, *bEx, *bRam, *bAg;   // mirror (read)
  u16 *mWv, *mWo, *mWhh, *mEx, *mRam, *mAg;         // mirror (write)
  float* out;
  float* ws;
};

// ---- ws layout (floats) ----
constexpr int CTRU   = 16384;    // 8 barrier regions x 2048 uints
constexpr int DL     = 16384;    // 3 x 4 floats (dl0, dl1, dl3)
constexpr int GT     = 16400;    // x@Wih accumulator, 8192
constexpr int NODE   = 24592;    // 5 x NODESZ
constexpr int NODESZ = 26624;
constexpr int THV = 0, ATT = 2048, GAC = 4096, EO = 12288, SO = 20480, CS = 22528, HP = 24576;
constexpr int FIN    = NODE + 5 * NODESZ;
constexpr int FINSZ  = 8192;
constexpr int ANC = 0, GCC = 2048, HNo = 4096, AGGo = 6144;
constexpr int RH1 = FIN + 3 * FINSZ;
constexpr int RF1 = RH1 + 2048;
constexpr int RC1 = RH1 + 4096;
constexpr int ZTOT = 5 * 20480 + 3 * 4096;
// bf16 mirror (element offsets): Wv 4M | Wo 4M | Whh 16M | Ex 16M | Ram 8M | Ag 8M
constexpr size_t BF_BYTE_OFF = 786432;
constexpr size_t oWo  = 4194304;
constexpr size_t oWhh = 8388608;
constexpr size_t oEx  = 25165824;
constexpr size_t oRam = 41943040;
constexpr size_t oAg  = 50331648;
constexpr size_t BF_NODE = 41943040;
constexpr size_t BF_ALL  = 58720256;

__device__ __forceinline__ float sigm(float v) { return 1.f / (1.f + expf(-v)); }

__device__ __forceinline__ float coh_f(const float* p) {
  return __hip_atomic_load(p, __ATOMIC_RELAXED, __HIP_MEMORY_SCOPE_AGENT);
}
__device__ __forceinline__ void coh_st(float* p, float v) {
  __hip_atomic_store(p, v, __ATOMIC_RELAXED, __HIP_MEMORY_SCOPE_AGENT);
}

__device__ __forceinline__ float bfl(unsigned u) { union { unsigned x; float f; } c; c.x = u << 16; return c.f; }
__device__ __forceinline__ float bfh(unsigned u) { union { unsigned x; float f; } c; c.x = u & 0xFFFF0000u; return c.f; }
__device__ __forceinline__ u16 f2bf(float f) {
  unsigned u = __float_as_uint(f);
  u += 0x7FFFu + ((u >> 16) & 1u);
  return (u16)(u >> 16);
}
__device__ __forceinline__ unsigned pk2(float a, float b) {
  return (unsigned)f2bf(a) | ((unsigned)f2bf(b) << 16);
}

template <typename WT> struct W4;
template <> struct W4<float> {
  static __device__ __forceinline__ void load(const float* p, float* w) {
    const float4 v = *reinterpret_cast<const float4*>(p);
    w[0] = v.x; w[1] = v.y; w[2] = v.z; w[3] = v.w;
  }
};
template <> struct W4<u16> {
  static __device__ __forceinline__ void load(const u16* p, float* w) {
    const uint2 u = *reinterpret_cast<const uint2*>(p);
    w[0] = bfl(u.x); w[1] = bfh(u.x); w[2] = bfl(u.y); w[3] = bfh(u.y);
  }
};

template <typename WT> __device__ __forceinline__ const WT* selWv(const P& p);
template <> __device__ __forceinline__ const float* selWv<float>(const P& p) { return p.Wv; }
template <> __device__ __forceinline__ const u16*   selWv<u16>(const P& p)   { return p.bWv; }
template <typename WT> __device__ __forceinline__ const WT* selWo(const P& p);
template <> __device__ __forceinline__ const float* selWo<float>(const P& p) { return p.Wo; }
template <> __device__ __forceinline__ const u16*   selWo<u16>(const P& p)   { return p.bWo; }
template <typename WT> __device__ __forceinline__ const WT* selWhh(const P& p);
template <> __device__ __forceinline__ const float* selWhh<float>(const P& p) { return p.Whh; }
template <> __device__ __forceinline__ const u16*   selWhh<u16>(const P& p)   { return p.bWhh; }
template <typename WT> __device__ __forceinline__ const WT* selEx(const P& p);
template <> __device__ __forceinline__ const float* selEx<float>(const P& p) { return p.expert_w; }
template <> __device__ __forceinline__ const u16*   selEx<u16>(const P& p)   { return p.bEx; }
template <typename WT> __device__ __forceinline__ const WT* selRam(const P& p);
template <> __device__ __forceinline__ const float* selRam<float>(const P& p) { return p.ram_w; }
template <> __device__ __forceinline__ const u16*   selRam<u16>(const P& p)   { return p.bRam; }
template <typename WT> __device__ __forceinline__ const WT* selAg(const P& p);
template <> __device__ __forceinline__ const float* selAg<float>(const P& p) { return p.ag_w; }
template <> __device__ __forceinline__ const u16*   selAg<u16>(const P& p)   { return p.bAg; }

__device__ __forceinline__ int dsteps(const float* dla, const float* drb, int mx) {
  const float l0 = coh_f(dla + 0) + drb[0];
  const float l1 = coh_f(dla + 1) + drb[1];
  const float l2 = coh_f(dla + 2) + drb[2];
  int ch = 0; float bv = l0;
  if (l1 > bv) { bv = l1; ch = 1; }
  if (l2 > bv) { bv = l2; ch = 2; }
  return ch < mx ? ch : mx;
}

// pred codes: 0 always | 1 s0>=1 | 2 s0>=1&&s1>=1 | 3 s0>=2 | 4 s0>=2&&s3>=1
__device__ __forceinline__ bool pred(const float* ws, const float* drb, int code) {
  if (code == 0) return true;
  const int s0 = dsteps(ws + DL, drb, 2);
  switch (code) {
    case 1: return s0 >= 1;
    case 2: return s0 >= 1 && dsteps(ws + DL + 4, drb, 1) >= 1;
    case 3: return s0 >= 2;
    case 4: return s0 >= 2 && dsteps(ws + DL + 8, drb, 1) >= 1;
  }
  return true;
}

// Tree barrier, 512 blocks. Region = 2048 uints (no overlap; R17 fix).
__device__ __forceinline__ void resbar(unsigned* ctr, int phase) {
  asm volatile("s_waitcnt vmcnt(0)" ::: "memory");
  __syncthreads();
  __shared__ int lastB;
  if (threadIdx.x == 0) {
    lastB = 0;
    unsigned* line = ctr + (blockIdx.x & 31) * 16;
    const unsigned prev = __hip_atomic_fetch_add(line, 1u, __ATOMIC_RELAXED, __HIP_MEMORY_SCOPE_AGENT);
    if (prev == (unsigned)(16 * phase) - 1u) {
      const unsigned m = __hip_atomic_fetch_add(ctr + 512, 1u, __ATOMIC_RELAXED, __HIP_MEMORY_SCOPE_AGENT);
      if (m == (unsigned)(32 * phase) - 1u) lastB = 1;
    }
  }
  __syncthreads();
  if (lastB) {
    if (threadIdx.x < 32)
      __hip_atomic_store(ctr + (40 + threadIdx.x) * 16, (unsigned)phase,
                         __ATOMIC_RELAXED, __HIP_MEMORY_SCOPE_AGENT);
  } else if (threadIdx.x == 0) {
    const unsigned* rel = ctr + (40 + (blockIdx.x & 31)) * 16;
    long t = 0;
    while (__hip_atomic_load(rel, __ATOMIC_RELAXED, __HIP_MEMORY_SCOPE_AGENT) < (unsigned)phase) {
      __builtin_amdgcn_s_sleep(2);
      if (++t > 30000000L) break;  // safety valve: fail absmax, not hang
    }
  }
  __syncthreads();
}

// Split-K GEMV phase. y[j] += sum x[i]*W[i,j].
// XMODE: 0 plain concat(xA,xB @ splitPt) | 1 coherent xA | 2 concat(xA, xBias+coh xB)
// CONV (WT=float only): nontemporal fp32 reads + write bf16 tile to convDst.
template <int CHUNK, int XMODE, typename WT, int CONV>
__device__ __forceinline__ void gemv_phase(
    int bid, int G,
    const float* xA, const float* xB, int splitPt, const float* xBias,
    const WT* __restrict__ W, float* __restrict__ y, int N,
    u16* convDst, float* shx, float4* red)
{
  const int tid = threadIdx.x, lane = tid & 63, tsub = tid >> 6;
  const int g = bid % G, s = bid / G;
  const int base = s * CHUNK;
  for (int idx = tid; idx < CHUNK; idx += 256) {
    const int i = base + idx;
    float v;
    if (XMODE == 0)      v = (i < splitPt) ? xA[i] : xB[i - splitPt];
    else if (XMODE == 1) v = coh_f(xA + i);
    else                 v = (i < splitPt) ? xA[i] : (xBias[i - splitPt] + coh_f(xB + (i - splitPt)));
    shx[idx] = v;
  }
  __syncthreads();
  constexpr int LEN = CHUNK / 4;
  const int j = (g << 8) + (lane << 2);
  const WT* Wp = W + (size_t)(base + tsub * LEN) * N + j;
  float ax = 0.f, ay = 0.f, az = 0.f, aw = 0.f;
#pragma unroll
  for (int t = 0; t < LEN; ++t) {
    const float xi = shx[tsub * LEN + t];
    float w[4];
    if constexpr (CONV) {
      const f4v a = __builtin_nontemporal_load(
          reinterpret_cast<const f4v*>(reinterpret_cast<const float*>(Wp) + (size_t)t * N));
      w[0] = a.x; w[1] = a.y; w[2] = a.z; w[3] = a.w;
      uint2 o; o.x = pk2(w[0], w[1]); o.y = pk2(w[2], w[3]);
      *reinterpret_cast<uint2*>(convDst + (size_t)(base + tsub * LEN + t) * N + j) = o;
    } else {
      W4<WT>::load(Wp + (size_t)t * N, w);
    }
    ax = fmaf(xi, w[0], ax); ay = fmaf(xi, w[1], ay);
    az = fmaf(xi, w[2], az); aw = fmaf(xi, w[3], aw);
  }
  red[tid] = make_float4(ax, ay, az, aw);
  __syncthreads();
  if (tsub == 0) {
    float4 a = red[tid], b = red[tid + 64], c = red[tid + 128], d = red[tid + 192];
    atomicAdd(&y[j + 0], a.x + b.x + c.x + d.x);
    atomicAdd(&y[j + 1], a.y + b.y + c.y + d.y);
    atomicAdd(&y[j + 2], a.z + b.z + c.z + d.z);
    atomicAdd(&y[j + 3], a.w + b.w + c.w + d.w);
  }
}

// Expert GEMV + fused LSTM (32 col-groups x 16 K-slices of 128 rows).
template <typename WT, int CONV>
__device__ void expert_phase(const P& p, float* nb, const float* c_in, const float* gt,
                             u16* convDst, float* shx, float4* red)
{
  const int tid = threadIdx.x, lane = tid & 63, w = tid >> 6;
  const int g = blockIdx.x & 31, s = blockIdx.x >> 5;
  const int i0 = s * 128;
  if (tid < 128) {
    const int i = i0 + tid;
    const float gi = p.b_lstm[i]         + coh_f(gt + i)         + coh_f(nb + GAC + i);
    const float gf = p.b_lstm[H + i]     + coh_f(gt + H + i)     + coh_f(nb + GAC + H + i);
    const float gg = p.b_lstm[2 * H + i] + coh_f(gt + 2 * H + i) + coh_f(nb + GAC + 2 * H + i);
    const float go = p.b_lstm[3 * H + i] + coh_f(gt + 3 * H + i) + coh_f(nb + GAC + 3 * H + i);
    const float c2 = sigm(gf) * c_in[i] + sigm(gi) * tanhf(gg);
    const float h2 = sigm(go) * tanhf(c2);
    shx[tid] = h2;
    if (g == 0) { coh_st(nb + SO + i, h2); coh_st(nb + CS + i, c2); }
  }
  __syncthreads();
  const int j = (g << 8) + (lane << 2);
  const int e = j >> 11, k = j & (H - 1);
  const size_t tileOff = ((size_t)e << 22) + (size_t)(i0 + w * 32) * H + k;
  const WT* Wp = selEx<WT>(p) + tileOff;
  float ax = 0.f, ay = 0.f, az = 0.f, aw = 0.f;
#pragma unroll
  for (int t = 0; t < 32; ++t) {
    const float xi = shx[w * 32 + t];
    float wv[4];
    if constexpr (CONV) {
      const f4v a = __builtin_nontemporal_load(
          reinterpret_cast<const f4v*>(reinterpret_cast<const float*>(Wp) + (size_t)t * H));
      wv[0] = a.x; wv[1] = a.y; wv[2] = a.z; wv[3] = a.w;
      uint2 o; o.x = pk2(wv[0], wv[1]); o.y = pk2(wv[2], wv[3]);
      *reinterpret_cast<uint2*>(convDst + tileOff + (size_t)t * H) = o;
    } else {
      W4<WT>::load(Wp + (size_t)t * H, wv);
    }
    ax = fmaf(xi, wv[0], ax); ay = fmaf(xi, wv[1], ay);
    az = fmaf(xi, wv[2], az); aw = fmaf(xi, wv[3], aw);
  }
  red[tid] = make_float4(ax, ay, az, aw);
  __syncthreads();
  if (w == 0) {
    float4 a = red[tid], b = red[tid + 64], c = red[tid + 128], d = red[tid + 192];
    atomicAdd(&nb[EO + j + 0], a.x + b.x + c.x + d.x);
    atomicAdd(&nb[EO + j + 1], a.y + b.y + c.y + d.y);
    atomicAdd(&nb[EO + j + 2], a.z + b.z + c.z + d.z);
    atomicAdd(&nb[EO + j + 3], a.w + b.w + c.w + d.w);
  }
}

// Combine phase: blocks 0..7.
__device__ void combine_phase(const P& p, float* nb, float* dla, int leaf, float damping,
                              const float* php, float* hn, float* agg, float4* red)
{
  const int tid = threadIdx.x;
  float r0 = 0.f, r1 = 0.f, r2 = 0.f, r3 = 0.f;
  for (int i = tid; i < H; i += 256) {
    const float hh = coh_f(nb + SO + i);
    const float4 rw = *reinterpret_cast<const float4*>(p.router_w + i * 4);
    r0 = fmaf(hh, rw.x, r0); r1 = fmaf(hh, rw.y, r1);
    r2 = fmaf(hh, rw.z, r2); r3 = fmaf(hh, rw.w, r3);
  }
  red[tid] = make_float4(r0, r1, r2, r3);
  __syncthreads();
  for (int off = 128; off > 0; off >>= 1) {
    if (tid < off) {
      const float4 b = red[tid + off];
      red[tid].x += b.x; red[tid].y += b.y; red[tid].z += b.z; red[tid].w += b.w;
    }
    __syncthreads();
  }
  const float4 L = red[0];
  __syncthreads();
  const float l0 = L.x + p.router_b[0], l1 = L.y + p.router_b[1];
  const float l2 = L.z + p.router_b[2], l3 = L.w + p.router_b[3];
  const float m = fmaxf(fmaxf(l0, l1), fmaxf(l2, l3));
  const float e0 = expf(l0 - m), e1 = expf(l1 - m), e2 = expf(l2 - m), e3 = expf(l3 - m);
  const float inv = 1.f / (e0 + e1 + e2 + e3);
  const float q0 = e0 * inv, q1 = e1 * inv, q2 = e2 * inv, q3 = e3 * inv;
  const int jj = blockIdx.x * 256 + tid;
  const float v = q0 * (p.expert_b[jj]         + coh_f(nb + EO + jj))
                + q1 * (p.expert_b[H + jj]     + coh_f(nb + EO + H + jj))
                + q2 * (p.expert_b[2 * H + jj] + coh_f(nb + EO + 2 * H + jj))
                + q3 * (p.expert_b[3 * H + jj] + coh_f(nb + EO + 3 * H + jj));
  if (leaf) {
    const float h0v = php[jj];
    const float hnv = h0v + damping * (v - h0v);
    hn[jj] = hnv;
    agg[jj] = h0v - 0.5f * hnv;
  } else {
    nb[HP + jj] = v;
    red[tid] = make_float4(v * p.dr_w[jj * 3 + 0], v * p.dr_w[jj * 3 + 1], v * p.dr_w[jj * 3 + 2], 0.f);
    __syncthreads();
    for (int off = 128; off > 0; off >>= 1) {
      if (tid < off) {
        const float4 b = red[tid + off];
        red[tid].x += b.x; red[tid].y += b.y; red[tid].z += b.z;
      }
      __syncthreads();
    }
    if (tid == 0) {
      atomicAdd(&dla[0], red[0].x);
      atomicAdd(&dla[1], red[0].y);
      atomicAdd(&dla[2], red[0].z);
    }
  }
}

// ---- tail phases (blocks 0..7) ----
__device__ void tail_fsel(const P& p, float* ws) {
  if (dsteps(ws + DL, p.dr_b, 2) < 1) return;
  const bool deep = dsteps(ws + DL + 4, p.dr_b, 1) >= 1;
  const int jj = blockIdx.x * 256 + threadIdx.x;
  const float* n1 = ws + NODE + 1 * NODESZ;
  const float* n2 = ws + NODE + 2 * NODESZ;
  const float* fb = ws + FIN;
  float rh, rf, rc;
  if (deep) {
    const float gacc = p.ag_b[jj] + coh_f(fb + GCC + jj);
    const float anc  = p.ram_b[jj] + coh_f(fb + ANC + jj);
    const float g = sigm(gacc);
    rh = g * anc + (1.f - g) * fb[HNo + jj];
    rf = n2[SO + jj]; rc = n2[CS + jj];
  } else {
    rh = n1[HP + jj]; rf = n1[SO + jj]; rc = n1[CS + jj];
  }
  ws[RH1 + jj] = rh; ws[RF1 + jj] = rf; ws[RC1 + jj] = rc;
}

__device__ void tail1(const P& p, float* ws) {
  const int s0 = dsteps(ws + DL, p.dr_b, 2);
  if (s0 < 1) return;
  const int jj = blockIdx.x * 256 + threadIdx.x;
  const float* n0 = ws + NODE;
  const float* n3 = ws + NODE + 3 * NODESZ;
  const float* n4 = ws + NODE + 4 * NODESZ;
  const float* fb3 = ws + FIN + FINSZ;
  float* fb0 = ws + FIN + 2 * FINSZ;
  const float r1 = ws[RH1 + jj];
  float rh3 = 0.f, rf3 = 0.f, rc3 = 0.f;
  if (s0 >= 2) {
    if (dsteps(ws + DL + 8, p.dr_b, 1) >= 1) {
      const float gacc = p.ag_b[jj] + coh_f(fb3 + GCC + jj);
      const float anc  = p.ram_b[jj] + coh_f(fb3 + ANC + jj);
      const float g = sigm(gacc);
      rh3 = g * anc + (1.f - g) * fb3[HNo + jj];
      rf3 = n4[SO + jj]; rc3 = n4[CS + jj];
    } else { rh3 = n3[HP + jj]; rf3 = n3[SO + jj]; rc3 = n3[CS + jj]; }
  }
  float ag = n0[HP + jj] - 0.5f * r1;
  float hc, oF, oC;
  if (s0 >= 2) { ag += (1.f / 3.f) * rh3; hc = rh3; oF = rf3; oC = rc3; }
  else { hc = r1; oF = ws[RF1 + jj]; oC = ws[RC1 + jj]; }
  fb0[AGGo + jj] = ag; fb0[HNo + jj] = hc;
  p.out[jj] = oF; p.out[2 * H + jj] = oC;
}

__device__ void tail2(const P& p, float* ws) {
  const int s0 = dsteps(ws + DL, p.dr_b, 2);
  const int jj = blockIdx.x * 256 + threadIdx.x;
  const float* n0 = ws + NODE;
  const float* fb0 = ws + FIN + 2 * FINSZ;
  if (s0 == 0) {
    p.out[jj] = n0[SO + jj]; p.out[H + jj] = n0[HP + jj]; p.out[2 * H + jj] = n0[CS + jj];
  } else {
    const float gacc = p.ag_b[jj] + coh_f(fb0 + GCC + jj);
    const float anc  = p.ram_b[jj] + coh_f(fb0 + ANC + jj);
    const float g = sigm(gacc);
    p.out[H + jj] = g * anc + (1.f - g) * fb0[HNo + jj];
  }
}

// ---- kernels ----
__global__ void __launch_bounds__(256) k_zero(P p) {
  float* ws = p.ws;
  const int gtid = blockIdx.x * 256 + threadIdx.x;
  const int gsz = gridDim.x * 256;
  unsigned* u = (unsigned*)ws;
  for (int i = gtid; i < CTRU; i += gsz) u[i] = 0u;
  if (gtid < 12) ws[DL + gtid] = 0.f;
  for (int i = gtid; i < 8192; i += gsz) ws[GT + i] = 0.f;
}

// Prep (2048 blocks): zero accumulators + Wih GEMV over all blocks (G=32,KS=64).
__global__ void __launch_bounds__(256) k_prep(P p) {
  float* ws = p.ws;
  __shared__ float shx[128];
  __shared__ float4 red[256];
  const size_t gtid = (size_t)blockIdx.x * 256 + threadIdx.x;
  const size_t nthr = (size_t)PREP_NB * 256;
  for (size_t i = gtid; i < (size_t)ZTOT; i += nthr) {
    if (i < 5 * 20480) {
      const int n = (int)(i / 20480), off = (int)(i % 20480);
      ws[NODE + n * NODESZ + off] = 0.f;
    } else {
      const int j = (int)(i - 5 * 20480);
      ws[FIN + (j >> 12) * FINSZ + (j & 4095)] = 0.f;
    }
  }
  gemv_phase<32, 0, float, 0>(blockIdx.x, 32, p.x, p.x, 1 << 30, nullptr,
                              p.Wih, ws + GT, 4 * H, nullptr, shx, red);
}

template <typename WT, int CONV>
__global__ void __launch_bounds__(256, 2) k_node(
    P p, int nodeIdx, int ctrIdx, int predCode,
    const float* hv, const float* cv,
    int leaf, float damping, const float* php, float* hn, float* agg, float* dla)
{
  float* ws = p.ws;
  if (!pred(ws, p.dr_b, predCode)) return;
  __shared__ float shx[128];
  __shared__ float4 red[256];
  float* nb = ws + NODE + nodeIdx * NODESZ;
  unsigned* ctr = (unsigned*)ws + ctrIdx * 2048;
  gemv_phase<32, 0, WT, CONV>(blockIdx.x, 8, hv, hv, 1 << 30, nullptr,
                              selWv<WT>(p), nb + THV, H, p.mWv, shx, red);
  resbar(ctr, 1);
  gemv_phase<32, 1, WT, CONV>(blockIdx.x, 8, nb + THV, nullptr, 0, nullptr,
                              selWo<WT>(p), nb + ATT, H, p.mWo, shx, red);
  resbar(ctr, 2);
  gemv_phase<128, 1, WT, CONV>(blockIdx.x, 32, nb + ATT, nullptr, 0, nullptr,
                               selWhh<WT>(p), nb + GAC, 4 * H, p.mWhh, shx, red);
  resbar(ctr, 3);
  expert_phase<WT, CONV>(p, nb, cv, ws + GT, p.mEx, shx, red);
  resbar(ctr, 4);
  if (blockIdx.x >= 8) return;
  combine_phase(p, nb, dla, leaf, damping, php, hn, agg, red);
}

// CONV=1 fin runs its GEMVs unconditionally (inputs pre-zeroed -> benign when
// pred is off) so the ram/ag mirror is always written; tails stay predicated.
template <typename WT, int CONV>
__global__ void __launch_bounds__(256, 2) k_fin(
    P p, int finIdx, int ctrIdx, int predCode,
    const float* aggv, const float* phpv, const float* hnv, int tailKind)
{
  float* ws = p.ws;
  __shared__ float shx[64];
  __shared__ float4 red[256];
  float* fb = ws + FIN + finIdx * FINSZ;
  unsigned* ctr = (unsigned*)ws + ctrIdx * 2048;
  const bool ok = pred(ws, p.dr_b, predCode);
  if (ok || CONV) {
    gemv_phase<64, 0, WT, CONV>(blockIdx.x, 8, aggv, phpv, H, nullptr,
                                selRam<WT>(p), fb + ANC, H, p.mRam, shx, red);
    resbar(ctr, 1);
    gemv_phase<64, 2, WT, CONV>(blockIdx.x, 8, hnv, fb + ANC, H, p.ram_b,
                                selAg<WT>(p), fb + GCC, H, p.mAg, shx, red);
    resbar(ctr, 2);
  }
  if (blockIdx.x >= 8) return;
  if (tailKind == 1) tail_fsel(p, ws);
  else if (tailKind == 2) tail1(p, ws);
  else tail2(p, ws);
}

extern "C" void kernel_launch(void* const* d_in, const int* in_sizes, int n_in,
                              void* d_out, int out_size, void* d_ws, size_t ws_size,
                              hipStream_t stream) {
  P p;
  p.x = (const float*)d_in[0];  p.h0 = (const float*)d_in[1];  p.c0 = (const float*)d_in[2];
  p.Wv = (const float*)d_in[5]; p.Wo = (const float*)d_in[6];
  p.Wih = (const float*)d_in[7]; p.Whh = (const float*)d_in[8];
  p.b_lstm = (const float*)d_in[9];
  p.router_w = (const float*)d_in[10]; p.router_b = (const float*)d_in[11];
  p.expert_w = (const float*)d_in[12]; p.expert_b = (const float*)d_in[13];
  p.dr_w = (const float*)d_in[14]; p.dr_b = (const float*)d_in[15];
  p.ram_w = (const float*)d_in[16]; p.ram_b = (const float*)d_in[17];
  p.ag_w = (const float*)d_in[18]; p.ag_b = (const float*)d_in[19];
  p.out = (float*)d_out;
  p.ws = (float*)d_ws;

  const bool useBf    = ws_size >= BF_BYTE_OFF + BF_NODE * 2 + 1024;
  const bool useBfFin = ws_size >= BF_BYTE_OFF + BF_ALL * 2 + 1024;
  u16* bf = (u16*)((char*)d_ws + BF_BYTE_OFF);
  p.bWv = bf;        p.bWo = bf + oWo;   p.bWhh = bf + oWhh;
  p.bEx = bf + oEx;  p.bRam = bf + oRam; p.bAg  = bf + oAg;
  p.mWv = bf;        p.mWo = bf + oWo;   p.mWhh = bf + oWhh;
  p.mEx = bf + oEx;  p.mRam = bf + oRam; p.mAg  = bf + oAg;

  float* ws = p.ws;
  auto nb = [&](int n) { return ws + NODE + n * NODESZ; };
  float* fb1 = ws + FIN;
  float* fb3 = ws + FIN + FINSZ;
  float* fb0 = ws + FIN + 2 * FINSZ;

  k_zero<<<16, 256, 0, stream>>>(p);
  k_prep<<<PREP_NB, 256, 0, stream>>>(p);

  // N0: convert-while-compute (fp32 NT reads -> bf16 mirror) if ws fits.
  if (useBf)
    k_node<float, 1><<<NB, 256, 0, stream>>>(p, 0, 0, 0, p.h0, p.c0, 0, 0.f,
                                             nullptr, nullptr, nullptr, ws + DL);
  else
    k_node<float, 0><<<NB, 256, 0, stream>>>(p, 0, 0, 0, p.h0, p.c0, 0, 0.f,
                                             nullptr, nullptr, nullptr, ws + DL);

  auto node = [&](int n, int ctrIdx, int predCode, const float* hv, const float* cv,
                  int leaf, float damping, const float* php, float* hn, float* agg, float* dla) {
    if (useBf)
      k_node<u16, 0><<<NB, 256, 0, stream>>>(p, n, ctrIdx, predCode, hv, cv, leaf, damping, php, hn, agg, dla);
    else
      k_node<float, 0><<<NB, 256, 0, stream>>>(p, n, ctrIdx, predCode, hv, cv, leaf, damping, php, hn, agg, dla);
  };

  // N1 (s0>=1)
  node(1, 1, 1, nb(0) + HP, nb(0) + CS, 0, 0.f, nullptr, nullptr, nullptr, ws + DL + 4);
  // N2 leaf (s0>=1 && s1>=1)
  node(2, 2, 2, nb(1) + HP, nb(1) + CS, 1, 0.25f, nb(1) + HP, fb1 + HNo, fb1 + AGGo, nullptr);
  // N1 finalize + fsel: fin1 converts ram/ag (unconditional GEMVs) if ws fits.
  if (useBfFin)
    k_fin<float, 1><<<NB, 256, 0, stream>>>(p, 0, 3, 2, fb1 + AGGo, nb(1) + HP, fb1 + HNo, 1);
  else
    k_fin<float, 0><<<NB, 256, 0, stream>>>(p, 0, 3, 2, fb1 + AGGo, nb(1) + HP, fb1 + HNo, 1);
  // N3 (s0>=2)
  node(3, 4, 3, ws + RH1, ws + RC1, 0, 0.f, nullptr, nullptr, nullptr, ws + DL + 8);
  // N4 leaf (s0>=2 && s3>=1)
  node(4, 5, 4, nb(3) + HP, nb(3) + CS, 1, 0.25f, nb(3) + HP, fb3 + HNo, fb3 + AGGo, nullptr);
  // N3 finalize + tail1
  if (useBfFin)
    k_fin<u16, 0><<<NB, 256, 0, stream>>>(p, 1, 6, 4, fb3 + AGGo, nb(3) + HP, fb3 + HNo, 2);
  else
    k_fin<float, 0><<<NB, 256, 0, stream>>>(p, 1, 6, 4, fb3 + AGGo, nb(3) + HP, fb3 + HNo, 2);
  // N0 finalize + tail2
  if (useBfFin)
    k_fin<u16, 0><<<NB, 256, 0, stream>>>(p, 2, 7, 1, fb0 + AGGo, nb(0) + HP, fb0 + HNo, 3);
  else
    k_fin<float, 0><<<NB, 256, 0, stream>>>(p, 2, 7, 1, fb0 + AGGo, nb(0) + HP, fb0 + HNo, 3);
}

// Round 19
// 337.642 us; speedup vs baseline: 1.0549x; 1.0238x over previous
//
#include <hip/hip_runtime.h>
#include <math.h>

// FractalOpponent on MI355X, round 19.
// = R18 with k_node/k_fin widened to 512 threads/block (same 512-block grid,
//   same barrier, same chunk geometry: each block splits its K-chunk 8 ways
//   instead of 4). 2x waves/CU for L3-latency hiding on the warm bf16 nodes.

#define H 2048
#define NB 512
#define PREP_NB 2048
typedef unsigned short u16;
typedef float f4v __attribute__((ext_vector_type(4)));

struct P {
  const float *x, *h0, *c0, *Wv, *Wo, *Wih, *Whh, *b_lstm, *router_w, *router_b,
              *expert_w, *expert_b, *dr_w, *dr_b, *ram_w, *ram_b, *ag_w, *ag_b;
  const u16 *bWv, *bWo, *bWhh, *bEx, *bRam, *bAg;
  u16 *mWv, *mWo, *mWhh, *mEx, *mRam, *mAg;
  float* out;
  float* ws;
};

// ---- ws layout (floats) ----
constexpr int CTRU   = 16384;
constexpr int DL     = 16384;
constexpr int GT     = 16400;
constexpr int NODE   = 24592;
constexpr int NODESZ = 26624;
constexpr int THV = 0, ATT = 2048, GAC = 4096, EO = 12288, SO = 20480, CS = 22528, HP = 24576;
constexpr int FIN    = NODE + 5 * NODESZ;
constexpr int FINSZ  = 8192;
constexpr int ANC = 0, GCC = 2048, HNo = 4096, AGGo = 6144;
constexpr int RH1 = FIN + 3 * FINSZ;
constexpr int RF1 = RH1 + 2048;
constexpr int RC1 = RH1 + 4096;
constexpr int ZTOT = 5 * 20480 + 3 * 4096;
constexpr size_t BF_BYTE_OFF = 786432;
constexpr size_t oWo  = 4194304;
constexpr size_t oWhh = 8388608;
constexpr size_t oEx  = 25165824;
constexpr size_t oRam = 41943040;
constexpr size_t oAg  = 50331648;
constexpr size_t BF_NODE = 41943040;
constexpr size_t BF_ALL  = 58720256;

__device__ __forceinline__ float sigm(float v) { return 1.f / (1.f + expf(-v)); }

__device__ __forceinline__ float coh_f(const float* p) {
  return __hip_atomic_load(p, __ATOMIC_RELAXED, __HIP_MEMORY_SCOPE_AGENT);
}
__device__ __forceinline__ void coh_st(float* p, float v) {
  __hip_atomic_store(p, v, __ATOMIC_RELAXED, __HIP_MEMORY_SCOPE_AGENT);
}

__device__ __forceinline__ float bfl(unsigned u) { union { unsigned x; float f; } c; c.x = u << 16; return c.f; }
__device__ __forceinline__ float bfh(unsigned u) { union { unsigned x; float f; } c; c.x = u & 0xFFFF0000u; return c.f; }
__device__ __forceinline__ u16 f2bf(float f) {
  unsigned u = __float_as_uint(f);
  u += 0x7FFFu + ((u >> 16) & 1u);
  return (u16)(u >> 16);
}
__device__ __forceinline__ unsigned pk2(float a, float b) {
  return (unsigned)f2bf(a) | ((unsigned)f2bf(b) << 16);
}

template <typename WT> struct W4;
template <> struct W4<float> {
  static __device__ __forceinline__ void load(const float* p, float* w) {
    const float4 v = *reinterpret_cast<const float4*>(p);
    w[0] = v.x; w[1] = v.y; w[2] = v.z; w[3] = v.w;
  }
};
template <> struct W4<u16> {
  static __device__ __forceinline__ void load(const u16* p, float* w) {
    const uint2 u = *reinterpret_cast<const uint2*>(p);
    w[0] = bfl(u.x); w[1] = bfh(u.x); w[2] = bfl(u.y); w[3] = bfh(u.y);
  }
};

template <typename WT> __device__ __forceinline__ const WT* selWv(const P& p);
template <> __device__ __forceinline__ const float* selWv<float>(const P& p) { return p.Wv; }
template <> __device__ __forceinline__ const u16*   selWv<u16>(const P& p)   { return p.bWv; }
template <typename WT> __device__ __forceinline__ const WT* selWo(const P& p);
template <> __device__ __forceinline__ const float* selWo<float>(const P& p) { return p.Wo; }
template <> __device__ __forceinline__ const u16*   selWo<u16>(const P& p)   { return p.bWo; }
template <typename WT> __device__ __forceinline__ const WT* selWhh(const P& p);
template <> __device__ __forceinline__ const float* selWhh<float>(const P& p) { return p.Whh; }
template <> __device__ __forceinline__ const u16*   selWhh<u16>(const P& p)   { return p.bWhh; }
template <typename WT> __device__ __forceinline__ const WT* selEx(const P& p);
template <> __device__ __forceinline__ const float* selEx<float>(const P& p) { return p.expert_w; }
template <> __device__ __forceinline__ const u16*   selEx<u16>(const P& p)   { return p.bEx; }
template <typename WT> __device__ __forceinline__ const WT* selRam(const P& p);
template <> __device__ __forceinline__ const float* selRam<float>(const P& p) { return p.ram_w; }
template <> __device__ __forceinline__ const u16*   selRam<u16>(const P& p)   { return p.bRam; }
template <typename WT> __device__ __forceinline__ const WT* selAg(const P& p);
template <> __device__ __forceinline__ const float* selAg<float>(const P& p) { return p.ag_w; }
template <> __device__ __forceinline__ const u16*   selAg<u16>(const P& p)   { return p.bAg; }

__device__ __forceinline__ int dsteps(const float* dla, const float* drb, int mx) {
  const float l0 = coh_f(dla + 0) + drb[0];
  const float l1 = coh_f(dla + 1) + drb[1];
  const float l2 = coh_f(dla + 2) + drb[2];
  int ch = 0; float bv = l0;
  if (l1 > bv) { bv = l1; ch = 1; }
  if (l2 > bv) { bv = l2; ch = 2; }
  return ch < mx ? ch : mx;
}

__device__ __forceinline__ bool pred(const float* ws, const float* drb, int code) {
  if (code == 0) return true;
  const int s0 = dsteps(ws + DL, drb, 2);
  switch (code) {
    case 1: return s0 >= 1;
    case 2: return s0 >= 1 && dsteps(ws + DL + 4, drb, 1) >= 1;
    case 3: return s0 >= 2;
    case 4: return s0 >= 2 && dsteps(ws + DL + 8, drb, 1) >= 1;
  }
  return true;
}

// Tree barrier, 512 blocks, region = 2048 uints.
__device__ __forceinline__ void resbar(unsigned* ctr, int phase) {
  asm volatile("s_waitcnt vmcnt(0)" ::: "memory");
  __syncthreads();
  __shared__ int lastB;
  if (threadIdx.x == 0) {
    lastB = 0;
    unsigned* line = ctr + (blockIdx.x & 31) * 16;
    const unsigned prev = __hip_atomic_fetch_add(line, 1u, __ATOMIC_RELAXED, __HIP_MEMORY_SCOPE_AGENT);
    if (prev == (unsigned)(16 * phase) - 1u) {
      const unsigned m = __hip_atomic_fetch_add(ctr + 512, 1u, __ATOMIC_RELAXED, __HIP_MEMORY_SCOPE_AGENT);
      if (m == (unsigned)(32 * phase) - 1u) lastB = 1;
    }
  }
  __syncthreads();
  if (lastB) {
    if (threadIdx.x < 32)
      __hip_atomic_store(ctr + (40 + threadIdx.x) * 16, (unsigned)phase,
                         __ATOMIC_RELAXED, __HIP_MEMORY_SCOPE_AGENT);
  } else if (threadIdx.x == 0) {
    const unsigned* rel = ctr + (40 + (blockIdx.x & 31)) * 16;
    long t = 0;
    while (__hip_atomic_load(rel, __ATOMIC_RELAXED, __HIP_MEMORY_SCOPE_AGENT) < (unsigned)phase) {
      __builtin_amdgcn_s_sleep(2);
      if (++t > 30000000L) break;  // safety valve
    }
  }
  __syncthreads();
}

// Split-K GEMV phase. y[j] += sum x[i]*W[i,j]. TPB = threads/block (256 or 512).
// Block covers CHUNK rows split NSUB=TPB/64 ways; 256 columns per col-group.
// XMODE: 0 plain concat | 1 coherent xA | 2 concat(xA, xBias+coh xB)
// CONV (WT=float): NT fp32 reads + bf16 mirror writes.
template <int CHUNK, int XMODE, typename WT, int CONV, int TPB>
__device__ __forceinline__ void gemv_phase(
    int bid, int G,
    const float* xA, const float* xB, int splitPt, const float* xBias,
    const WT* __restrict__ W, float* __restrict__ y, int N,
    u16* convDst, float* shx, float4* red)
{
  constexpr int NSUB = TPB / 64;
  constexpr int LEN  = CHUNK / NSUB;
  const int tid = threadIdx.x, lane = tid & 63, tsub = tid >> 6;
  const int g = bid % G, s = bid / G;
  const int base = s * CHUNK;
  for (int idx = tid; idx < CHUNK; idx += TPB) {
    const int i = base + idx;
    float v;
    if (XMODE == 0)      v = (i < splitPt) ? xA[i] : xB[i - splitPt];
    else if (XMODE == 1) v = coh_f(xA + i);
    else                 v = (i < splitPt) ? xA[i] : (xBias[i - splitPt] + coh_f(xB + (i - splitPt)));
    shx[idx] = v;
  }
  __syncthreads();
  const int j = (g << 8) + (lane << 2);
  const WT* Wp = W + (size_t)(base + tsub * LEN) * N + j;
  float ax = 0.f, ay = 0.f, az = 0.f, aw = 0.f;
#pragma unroll
  for (int t = 0; t < LEN; ++t) {
    const float xi = shx[tsub * LEN + t];
    float w[4];
    if constexpr (CONV) {
      const f4v a = __builtin_nontemporal_load(
          reinterpret_cast<const f4v*>(reinterpret_cast<const float*>(Wp) + (size_t)t * N));
      w[0] = a.x; w[1] = a.y; w[2] = a.z; w[3] = a.w;
      uint2 o; o.x = pk2(w[0], w[1]); o.y = pk2(w[2], w[3]);
      *reinterpret_cast<uint2*>(convDst + (size_t)(base + tsub * LEN + t) * N + j) = o;
    } else {
      W4<WT>::load(Wp + (size_t)t * N, w);
    }
    ax = fmaf(xi, w[0], ax); ay = fmaf(xi, w[1], ay);
    az = fmaf(xi, w[2], az); aw = fmaf(xi, w[3], aw);
  }
  red[tid] = make_float4(ax, ay, az, aw);
  __syncthreads();
  if (tsub == 0) {
    float4 a = red[tid];
#pragma unroll
    for (int q = 1; q < NSUB; ++q) {
      const float4 b = red[tid + q * 64];
      a.x += b.x; a.y += b.y; a.z += b.z; a.w += b.w;
    }
    atomicAdd(&y[j + 0], a.x);
    atomicAdd(&y[j + 1], a.y);
    atomicAdd(&y[j + 2], a.z);
    atomicAdd(&y[j + 3], a.w);
  }
}

// Expert GEMV + fused LSTM, TPB=512 (32 col-groups x 16 K-slices of 128 rows,
// each block's 8 wave-groups cover 16 rows apiece).
template <typename WT, int CONV>
__device__ void expert_phase(const P& p, float* nb, const float* c_in, const float* gt,
                             u16* convDst, float* shx, float4* red)
{
  const int tid = threadIdx.x, lane = tid & 63, w = tid >> 6;
  const int g = blockIdx.x & 31, s = blockIdx.x >> 5;
  const int i0 = s * 128;
  if (tid < 128) {
    const int i = i0 + tid;
    const float gi = p.b_lstm[i]         + coh_f(gt + i)         + coh_f(nb + GAC + i);
    const float gf = p.b_lstm[H + i]     + coh_f(gt + H + i)     + coh_f(nb + GAC + H + i);
    const float gg = p.b_lstm[2 * H + i] + coh_f(gt + 2 * H + i) + coh_f(nb + GAC + 2 * H + i);
    const float go = p.b_lstm[3 * H + i] + coh_f(gt + 3 * H + i) + coh_f(nb + GAC + 3 * H + i);
    const float c2 = sigm(gf) * c_in[i] + sigm(gi) * tanhf(gg);
    const float h2 = sigm(go) * tanhf(c2);
    shx[tid] = h2;
    if (g == 0) { coh_st(nb + SO + i, h2); coh_st(nb + CS + i, c2); }
  }
  __syncthreads();
  const int j = (g << 8) + (lane << 2);
  const int e = j >> 11, k = j & (H - 1);
  const size_t tileOff = ((size_t)e << 22) + (size_t)(i0 + w * 16) * H + k;
  const WT* Wp = selEx<WT>(p) + tileOff;
  float ax = 0.f, ay = 0.f, az = 0.f, aw = 0.f;
#pragma unroll
  for (int t = 0; t < 16; ++t) {
    const float xi = shx[w * 16 + t];
    float wv[4];
    if constexpr (CONV) {
      const f4v a = __builtin_nontemporal_load(
          reinterpret_cast<const f4v*>(reinterpret_cast<const float*>(Wp) + (size_t)t * H));
      wv[0] = a.x; wv[1] = a.y; wv[2] = a.z; wv[3] = a.w;
      uint2 o; o.x = pk2(wv[0], wv[1]); o.y = pk2(wv[2], wv[3]);
      *reinterpret_cast<uint2*>(convDst + tileOff + (size_t)t * H) = o;
    } else {
      W4<WT>::load(Wp + (size_t)t * H, wv);
    }
    ax = fmaf(xi, wv[0], ax); ay = fmaf(xi, wv[1], ay);
    az = fmaf(xi, wv[2], az); aw = fmaf(xi, wv[3], aw);
  }
  red[tid] = make_float4(ax, ay, az, aw);
  __syncthreads();
  if (w == 0) {
    float4 a = red[tid];
#pragma unroll
    for (int q = 1; q < 8; ++q) {
      const float4 b = red[tid + q * 64];
      a.x += b.x; a.y += b.y; a.z += b.z; a.w += b.w;
    }
    atomicAdd(&nb[EO + j + 0], a.x);
    atomicAdd(&nb[EO + j + 1], a.y);
    atomicAdd(&nb[EO + j + 2], a.z);
    atomicAdd(&nb[EO + j + 3], a.w);
  }
}

// Combine phase: blocks 0..7, TPB=512 (per-jj work on tid<256).
__device__ void combine_phase(const P& p, float* nb, float* dla, int leaf, float damping,
                              const float* php, float* hn, float* agg, float4* red)
{
  const int tid = threadIdx.x;
  float r0 = 0.f, r1 = 0.f, r2 = 0.f, r3 = 0.f;
  for (int i = tid; i < H; i += 512) {
    const float hh = coh_f(nb + SO + i);
    const float4 rw = *reinterpret_cast<const float4*>(p.router_w + i * 4);
    r0 = fmaf(hh, rw.x, r0); r1 = fmaf(hh, rw.y, r1);
    r2 = fmaf(hh, rw.z, r2); r3 = fmaf(hh, rw.w, r3);
  }
  red[tid] = make_float4(r0, r1, r2, r3);
  __syncthreads();
  for (int off = 256; off > 0; off >>= 1) {
    if (tid < off) {
      const float4 b = red[tid + off];
      red[tid].x += b.x; red[tid].y += b.y; red[tid].z += b.z; red[tid].w += b.w;
    }
    __syncthreads();
  }
  const float4 L = red[0];
  __syncthreads();
  const float l0 = L.x + p.router_b[0], l1 = L.y + p.router_b[1];
  const float l2 = L.z + p.router_b[2], l3 = L.w + p.router_b[3];
  const float m = fmaxf(fmaxf(l0, l1), fmaxf(l2, l3));
  const float e0 = expf(l0 - m), e1 = expf(l1 - m), e2 = expf(l2 - m), e3 = expf(l3 - m);
  const float inv = 1.f / (e0 + e1 + e2 + e3);
  const float q0 = e0 * inv, q1 = e1 * inv, q2 = e2 * inv, q3 = e3 * inv;
  const int jj = blockIdx.x * 256 + (tid & 255);
  float v = 0.f;
  if (tid < 256) {
    v = q0 * (p.expert_b[jj]         + coh_f(nb + EO + jj))
      + q1 * (p.expert_b[H + jj]     + coh_f(nb + EO + H + jj))
      + q2 * (p.expert_b[2 * H + jj] + coh_f(nb + EO + 2 * H + jj))
      + q3 * (p.expert_b[3 * H + jj] + coh_f(nb + EO + 3 * H + jj));
  }
  if (leaf) {
    if (tid < 256) {
      const float h0v = php[jj];
      const float hnv = h0v + damping * (v - h0v);
      hn[jj] = hnv;
      agg[jj] = h0v - 0.5f * hnv;
    }
  } else {
    if (tid < 256) nb[HP + jj] = v;
    red[tid] = (tid < 256)
        ? make_float4(v * p.dr_w[jj * 3 + 0], v * p.dr_w[jj * 3 + 1], v * p.dr_w[jj * 3 + 2], 0.f)
        : make_float4(0.f, 0.f, 0.f, 0.f);
    __syncthreads();
    for (int off = 256; off > 0; off >>= 1) {
      if (tid < off) {
        const float4 b = red[tid + off];
        red[tid].x += b.x; red[tid].y += b.y; red[tid].z += b.z;
      }
      __syncthreads();
    }
    if (tid == 0) {
      atomicAdd(&dla[0], red[0].x);
      atomicAdd(&dla[1], red[0].y);
      atomicAdd(&dla[2], red[0].z);
    }
  }
}

// ---- tails (blocks 0..7, tid<256 active; no __syncthreads inside) ----
__device__ void tail_fsel(const P& p, float* ws) {
  if (threadIdx.x >= 256) return;
  if (dsteps(ws + DL, p.dr_b, 2) < 1) return;
  const bool deep = dsteps(ws + DL + 4, p.dr_b, 1) >= 1;
  const int jj = blockIdx.x * 256 + threadIdx.x;
  const float* n1 = ws + NODE + 1 * NODESZ;
  const float* n2 = ws + NODE + 2 * NODESZ;
  const float* fb = ws + FIN;
  float rh, rf, rc;
  if (deep) {
    const float gacc = p.ag_b[jj] + coh_f(fb + GCC + jj);
    const float anc  = p.ram_b[jj] + coh_f(fb + ANC + jj);
    const float g = sigm(gacc);
    rh = g * anc + (1.f - g) * fb[HNo + jj];
    rf = n2[SO + jj]; rc = n2[CS + jj];
  } else {
    rh = n1[HP + jj]; rf = n1[SO + jj]; rc = n1[CS + jj];
  }
  ws[RH1 + jj] = rh; ws[RF1 + jj] = rf; ws[RC1 + jj] = rc;
}

__device__ void tail1(const P& p, float* ws) {
  if (threadIdx.x >= 256) return;
  const int s0 = dsteps(ws + DL, p.dr_b, 2);
  if (s0 < 1) return;
  const int jj = blockIdx.x * 256 + threadIdx.x;
  const float* n0 = ws + NODE;
  const float* n3 = ws + NODE + 3 * NODESZ;
  const float* n4 = ws + NODE + 4 * NODESZ;
  const float* fb3 = ws + FIN + FINSZ;
  float* fb0 = ws + FIN + 2 * FINSZ;
  const float r1 = ws[RH1 + jj];
  float rh3 = 0.f, rf3 = 0.f, rc3 = 0.f;
  if (s0 >= 2) {
    if (dsteps(ws + DL + 8, p.dr_b, 1) >= 1) {
      const float gacc = p.ag_b[jj] + coh_f(fb3 + GCC + jj);
      const float anc  = p.ram_b[jj] + coh_f(fb3 + ANC + jj);
      const float g = sigm(gacc);
      rh3 = g * anc + (1.f - g) * fb3[HNo + jj];
      rf3 = n4[SO + jj]; rc3 = n4[CS + jj];
    } else { rh3 = n3[HP + jj]; rf3 = n3[SO + jj]; rc3 = n3[CS + jj]; }
  }
  float ag = n0[HP + jj] - 0.5f * r1;
  float hc, oF, oC;
  if (s0 >= 2) { ag += (1.f / 3.f) * rh3; hc = rh3; oF = rf3; oC = rc3; }
  else { hc = r1; oF = ws[RF1 + jj]; oC = ws[RC1 + jj]; }
  fb0[AGGo + jj] = ag; fb0[HNo + jj] = hc;
  p.out[jj] = oF; p.out[2 * H + jj] = oC;
}

__device__ void tail2(const P& p, float* ws) {
  if (threadIdx.x >= 256) return;
  const int s0 = dsteps(ws + DL, p.dr_b, 2);
  const int jj = blockIdx.x * 256 + threadIdx.x;
  const float* n0 = ws + NODE;
  const float* fb0 = ws + FIN + 2 * FINSZ;
  if (s0 == 0) {
    p.out[jj] = n0[SO + jj]; p.out[H + jj] = n0[HP + jj]; p.out[2 * H + jj] = n0[CS + jj];
  } else {
    const float gacc = p.ag_b[jj] + coh_f(fb0 + GCC + jj);
    const float anc  = p.ram_b[jj] + coh_f(fb0 + ANC + jj);
    const float g = sigm(gacc);
    p.out[H + jj] = g * anc + (1.f - g) * fb0[HNo + jj];
  }
}

// ---- kernels ----
__global__ void __launch_bounds__(256) k_zero(P p) {
  float* ws = p.ws;
  const int gtid = blockIdx.x * 256 + threadIdx.x;
  const int gsz = gridDim.x * 256;
  unsigned* u = (unsigned*)ws;
  for (int i = gtid; i < CTRU; i += gsz) u[i] = 0u;
  if (gtid < 12) ws[DL + gtid] = 0.f;
  for (int i = gtid; i < 8192; i += gsz) ws[GT + i] = 0.f;
}

__global__ void __launch_bounds__(256) k_prep(P p) {
  float* ws = p.ws;
  __shared__ float shx[128];
  __shared__ float4 red[256];
  const size_t gtid = (size_t)blockIdx.x * 256 + threadIdx.x;
  const size_t nthr = (size_t)PREP_NB * 256;
  for (size_t i = gtid; i < (size_t)ZTOT; i += nthr) {
    if (i < 5 * 20480) {
      const int n = (int)(i / 20480), off = (int)(i % 20480);
      ws[NODE + n * NODESZ + off] = 0.f;
    } else {
      const int j = (int)(i - 5 * 20480);
      ws[FIN + (j >> 12) * FINSZ + (j & 4095)] = 0.f;
    }
  }
  gemv_phase<32, 0, float, 0, 256>(blockIdx.x, 32, p.x, p.x, 1 << 30, nullptr,
                                   p.Wih, ws + GT, 4 * H, nullptr, shx, red);
}

template <typename WT, int CONV>
__global__ void __launch_bounds__(512, 2) k_node(
    P p, int nodeIdx, int ctrIdx, int predCode,
    const float* hv, const float* cv,
    int leaf, float damping, const float* php, float* hn, float* agg, float* dla)
{
  float* ws = p.ws;
  if (!pred(ws, p.dr_b, predCode)) return;
  __shared__ float shx[128];
  __shared__ float4 red[512];
  float* nb = ws + NODE + nodeIdx * NODESZ;
  unsigned* ctr = (unsigned*)ws + ctrIdx * 2048;
  gemv_phase<32, 0, WT, CONV, 512>(blockIdx.x, 8, hv, hv, 1 << 30, nullptr,
                                   selWv<WT>(p), nb + THV, H, p.mWv, shx, red);
  resbar(ctr, 1);
  gemv_phase<32, 1, WT, CONV, 512>(blockIdx.x, 8, nb + THV, nullptr, 0, nullptr,
                                   selWo<WT>(p), nb + ATT, H, p.mWo, shx, red);
  resbar(ctr, 2);
  gemv_phase<128, 1, WT, CONV, 512>(blockIdx.x, 32, nb + ATT, nullptr, 0, nullptr,
                                    selWhh<WT>(p), nb + GAC, 4 * H, p.mWhh, shx, red);
  resbar(ctr, 3);
  expert_phase<WT, CONV>(p, nb, cv, ws + GT, p.mEx, shx, red);
  resbar(ctr, 4);
  if (blockIdx.x >= 8) return;
  combine_phase(p, nb, dla, leaf, damping, php, hn, agg, red);
}

template <typename WT, int CONV>
__global__ void __launch_bounds__(512, 2) k_fin(
    P p, int finIdx, int ctrIdx, int predCode,
    const float* aggv, const float* phpv, const float* hnv, int tailKind)
{
  float* ws = p.ws;
  __shared__ float shx[64];
  __shared__ float4 red[512];
  float* fb = ws + FIN + finIdx * FINSZ;
  unsigned* ctr = (unsigned*)ws + ctrIdx * 2048;
  const bool ok = pred(ws, p.dr_b, predCode);
  if (ok || CONV) {
    gemv_phase<64, 0, WT, CONV, 512>(blockIdx.x, 8, aggv, phpv, H, nullptr,
                                     selRam<WT>(p), fb + ANC, H, p.mRam, shx, red);
    resbar(ctr, 1);
    gemv_phase<64, 2, WT, CONV, 512>(blockIdx.x, 8, hnv, fb + ANC, H, p.ram_b,
                                     selAg<WT>(p), fb + GCC, H, p.mAg, shx, red);
    resbar(ctr, 2);
  }
  if (blockIdx.x >= 8) return;
  if (tailKind == 1) tail_fsel(p, ws);
  else if (tailKind == 2) tail1(p, ws);
  else tail2(p, ws);
}

extern "C" void kernel_launch(void* const* d_in, const int* in_sizes, int n_in,
                              void* d_out, int out_size, void* d_ws, size_t ws_size,
                              hipStream_t stream) {
  P p;
  p.x = (const float*)d_in[0];  p.h0 = (const float*)d_in[1];  p.c0 = (const float*)d_in[2];
  p.Wv = (const float*)d_in[5]; p.Wo = (const float*)d_in[6];
  p.Wih = (const float*)d_in[7]; p.Whh = (const float*)d_in[8];
  p.b_lstm = (const float*)d_in[9];
  p.router_w = (const float*)d_in[10]; p.router_b = (const float*)d_in[11];
  p.expert_w = (const float*)d_in[12]; p.expert_b = (const float*)d_in[13];
  p.dr_w = (const float*)d_in[14]; p.dr_b = (const float*)d_in[15];
  p.ram_w = (const float*)d_in[16]; p.ram_b = (const float*)d_in[17];
  p.ag_w = (const float*)d_in[18]; p.ag_b = (const float*)d_in[19];
  p.out = (float*)d_out;
  p.ws = (float*)d_ws;

  const bool useBf    = ws_size >= BF_BYTE_OFF + BF_NODE * 2 + 1024;
  const bool useBfFin = ws_size >= BF_BYTE_OFF + BF_ALL * 2 + 1024;
  u16* bf = (u16*)((char*)d_ws + BF_BYTE_OFF);
  p.bWv = bf;        p.bWo = bf + oWo;   p.bWhh = bf + oWhh;
  p.bEx = bf + oEx;  p.bRam = bf + oRam; p.bAg  = bf + oAg;
  p.mWv = bf;        p.mWo = bf + oWo;   p.mWhh = bf + oWhh;
  p.mEx = bf + oEx;  p.mRam = bf + oRam; p.mAg  = bf + oAg;

  float* ws = p.ws;
  auto nb = [&](int n) { return ws + NODE + n * NODESZ; };
  float* fb1 = ws + FIN;
  float* fb3 = ws + FIN + FINSZ;
  float* fb0 = ws + FIN + 2 * FINSZ;

  k_zero<<<16, 256, 0, stream>>>(p);
  k_prep<<<PREP_NB, 256, 0, stream>>>(p);

  if (useBf)
    k_node<float, 1><<<NB, 512, 0, stream>>>(p, 0, 0, 0, p.h0, p.c0, 0, 0.f,
                                             nullptr, nullptr, nullptr, ws + DL);
  else
    k_node<float, 0><<<NB, 512, 0, stream>>>(p, 0, 0, 0, p.h0, p.c0, 0, 0.f,
                                             nullptr, nullptr, nullptr, ws + DL);

  auto node = [&](int n, int ctrIdx, int predCode, const float* hv, const float* cv,
                  int leaf, float damping, const float* php, float* hn, float* agg, float* dla) {
    if (useBf)
      k_node<u16, 0><<<NB, 512, 0, stream>>>(p, n, ctrIdx, predCode, hv, cv, leaf, damping, php, hn, agg, dla);
    else
      k_node<float, 0><<<NB, 512, 0, stream>>>(p, n, ctrIdx, predCode, hv, cv, leaf, damping, php, hn, agg, dla);
  };

  node(1, 1, 1, nb(0) + HP, nb(0) + CS, 0, 0.f, nullptr, nullptr, nullptr, ws + DL + 4);
  node(2, 2, 2, nb(1) + HP, nb(1) + CS, 1, 0.25f, nb(1) + HP, fb1 + HNo, fb1 + AGGo, nullptr);
  if (useBfFin)
    k_fin<float, 1><<<NB, 512, 0, stream>>>(p, 0, 3, 2, fb1 + AGGo, nb(1) + HP, fb1 + HNo, 1);
  else
    k_fin<float, 0><<<NB, 512, 0, stream>>>(p, 0, 3, 2, fb1 + AGGo, nb(1) + HP, fb1 + HNo, 1);
  node(3, 4, 3, ws + RH1, ws + RC1, 0, 0.f, nullptr, nullptr, nullptr, ws + DL + 8);
  node(4, 5, 4, nb(3) + HP, nb(3) + CS, 1, 0.25f, nb(3) + HP, fb3 + HNo, fb3 + AGGo, nullptr);
  if (useBfFin)
    k_fin<u16, 0><<<NB, 512, 0, stream>>>(p, 1, 6, 4, fb3 + AGGo, nb(3) + HP, fb3 + HNo, 2);
  else
    k_fin<float, 0><<<NB, 512, 0, stream>>>(p, 1, 6, 4, fb3 + AGGo, nb(3) + HP, fb3 + HNo, 2);
  if (useBfFin)
    k_fin<u16, 0><<<NB, 512, 0, stream>>>(p, 2, 7, 1, fb0 + AGGo, nb(0) + HP, fb0 + HNo, 3);
  else
    k_fin<float, 0><<<NB, 512, 0, stream>>>(p, 2, 7, 1, fb0 + AGGo, nb(0) + HP, fb0 + HNo, 3);
}

// Round 20
// 337.577 us; speedup vs baseline: 1.0551x; 1.0002x over previous
//
#include <hip/hip_runtime.h>
#include <math.h>

// FractalOpponent on MI355X, round 20.
// = R19 with continuation-fusion of the small fin kernels:
//   [N2 + fin0 + fsel] and [N4 + fin1 + tail1 + fin2 + tail2] become single
//   kernels (running phase counters; preds are uniform across blocks).
//   10 -> 7 launches. Intra-kernel cross-block edges use coherent ld/st.

#define H 2048
#define NB 512
#define PREP_NB 2048
typedef unsigned short u16;
typedef float f4v __attribute__((ext_vector_type(4)));

struct P {
  const float *x, *h0, *c0, *Wv, *Wo, *Wih, *Whh, *b_lstm, *router_w, *router_b,
              *expert_w, *expert_b, *dr_w, *dr_b, *ram_w, *ram_b, *ag_w, *ag_b;
  const u16 *bWv, *bWo, *bWhh, *bEx, *bRam, *bAg;
  u16 *mWv, *mWo, *mWhh, *mEx, *mRam, *mAg;
  float* out;
  float* ws;
};

// ---- ws layout (floats) ----
constexpr int CTRU   = 16384;    // 8 barrier regions x 2048 uints
constexpr int DL     = 16384;
constexpr int GT     = 16400;
constexpr int NODE   = 24592;
constexpr int NODESZ = 26624;
constexpr int THV = 0, ATT = 2048, GAC = 4096, EO = 12288, SO = 20480, CS = 22528, HP = 24576;
constexpr int FIN    = NODE + 5 * NODESZ;
constexpr int FINSZ  = 8192;
constexpr int ANC = 0, GCC = 2048, HNo = 4096, AGGo = 6144;
constexpr int RH1 = FIN + 3 * FINSZ;
constexpr int RF1 = RH1 + 2048;
constexpr int RC1 = RH1 + 4096;
constexpr int ZTOT = 5 * 20480 + 3 * 4096;
constexpr size_t BF_BYTE_OFF = 786432;
constexpr size_t oWo  = 4194304;
constexpr size_t oWhh = 8388608;
constexpr size_t oEx  = 25165824;
constexpr size_t oRam = 41943040;
constexpr size_t oAg  = 50331648;
constexpr size_t BF_NODE = 41943040;
constexpr size_t BF_ALL  = 58720256;

__device__ __forceinline__ float sigm(float v) { return 1.f / (1.f + expf(-v)); }

__device__ __forceinline__ float coh_f(const float* p) {
  return __hip_atomic_load(p, __ATOMIC_RELAXED, __HIP_MEMORY_SCOPE_AGENT);
}
__device__ __forceinline__ void coh_st(float* p, float v) {
  __hip_atomic_store(p, v, __ATOMIC_RELAXED, __HIP_MEMORY_SCOPE_AGENT);
}

__device__ __forceinline__ float bfl(unsigned u) { union { unsigned x; float f; } c; c.x = u << 16; return c.f; }
__device__ __forceinline__ float bfh(unsigned u) { union { unsigned x; float f; } c; c.x = u & 0xFFFF0000u; return c.f; }
__device__ __forceinline__ u16 f2bf(float f) {
  unsigned u = __float_as_uint(f);
  u += 0x7FFFu + ((u >> 16) & 1u);
  return (u16)(u >> 16);
}
__device__ __forceinline__ unsigned pk2(float a, float b) {
  return (unsigned)f2bf(a) | ((unsigned)f2bf(b) << 16);
}

template <typename WT> struct W4;
template <> struct W4<float> {
  static __device__ __forceinline__ void load(const float* p, float* w) {
    const float4 v = *reinterpret_cast<const float4*>(p);
    w[0] = v.x; w[1] = v.y; w[2] = v.z; w[3] = v.w;
  }
};
template <> struct W4<u16> {
  static __device__ __forceinline__ void load(const u16* p, float* w) {
    const uint2 u = *reinterpret_cast<const uint2*>(p);
    w[0] = bfl(u.x); w[1] = bfh(u.x); w[2] = bfl(u.y); w[3] = bfh(u.y);
  }
};

template <typename WT> __device__ __forceinline__ const WT* selWv(const P& p);
template <> __device__ __forceinline__ const float* selWv<float>(const P& p) { return p.Wv; }
template <> __device__ __forceinline__ const u16*   selWv<u16>(const P& p)   { return p.bWv; }
template <typename WT> __device__ __forceinline__ const WT* selWo(const P& p);
template <> __device__ __forceinline__ const float* selWo<float>(const P& p) { return p.Wo; }
template <> __device__ __forceinline__ const u16*   selWo<u16>(const P& p)   { return p.bWo; }
template <typename WT> __device__ __forceinline__ const WT* selWhh(const P& p);
template <> __device__ __forceinline__ const float* selWhh<float>(const P& p) { return p.Whh; }
template <> __device__ __forceinline__ const u16*   selWhh<u16>(const P& p)   { return p.bWhh; }
template <typename WT> __device__ __forceinline__ const WT* selEx(const P& p);
template <> __device__ __forceinline__ const float* selEx<float>(const P& p) { return p.expert_w; }
template <> __device__ __forceinline__ const u16*   selEx<u16>(const P& p)   { return p.bEx; }
template <typename WT> __device__ __forceinline__ const WT* selRam(const P& p);
template <> __device__ __forceinline__ const float* selRam<float>(const P& p) { return p.ram_w; }
template <> __device__ __forceinline__ const u16*   selRam<u16>(const P& p)   { return p.bRam; }
template <typename WT> __device__ __forceinline__ const WT* selAg(const P& p);
template <> __device__ __forceinline__ const float* selAg<float>(const P& p) { return p.ag_w; }
template <> __device__ __forceinline__ const u16*   selAg<u16>(const P& p)   { return p.bAg; }

__device__ __forceinline__ int dsteps(const float* dla, const float* drb, int mx) {
  const float l0 = coh_f(dla + 0) + drb[0];
  const float l1 = coh_f(dla + 1) + drb[1];
  const float l2 = coh_f(dla + 2) + drb[2];
  int ch = 0; float bv = l0;
  if (l1 > bv) { bv = l1; ch = 1; }
  if (l2 > bv) { bv = l2; ch = 2; }
  return ch < mx ? ch : mx;
}

__device__ __forceinline__ bool pred(const float* ws, const float* drb, int code) {
  if (code == 0) return true;
  const int s0 = dsteps(ws + DL, drb, 2);
  switch (code) {
    case 1: return s0 >= 1;
    case 2: return s0 >= 1 && dsteps(ws + DL + 4, drb, 1) >= 1;
    case 3: return s0 >= 2;
    case 4: return s0 >= 2 && dsteps(ws + DL + 8, drb, 1) >= 1;
  }
  return true;
}

// Tree barrier, 512 blocks, region = 2048 uints.
__device__ __forceinline__ void resbar(unsigned* ctr, int phase) {
  asm volatile("s_waitcnt vmcnt(0)" ::: "memory");
  __syncthreads();
  __shared__ int lastB;
  if (threadIdx.x == 0) {
    lastB = 0;
    unsigned* line = ctr + (blockIdx.x & 31) * 16;
    const unsigned prev = __hip_atomic_fetch_add(line, 1u, __ATOMIC_RELAXED, __HIP_MEMORY_SCOPE_AGENT);
    if (prev == (unsigned)(16 * phase) - 1u) {
      const unsigned m = __hip_atomic_fetch_add(ctr + 512, 1u, __ATOMIC_RELAXED, __HIP_MEMORY_SCOPE_AGENT);
      if (m == (unsigned)(32 * phase) - 1u) lastB = 1;
    }
  }
  __syncthreads();
  if (lastB) {
    if (threadIdx.x < 32)
      __hip_atomic_store(ctr + (40 + threadIdx.x) * 16, (unsigned)phase,
                         __ATOMIC_RELAXED, __HIP_MEMORY_SCOPE_AGENT);
  } else if (threadIdx.x == 0) {
    const unsigned* rel = ctr + (40 + (blockIdx.x & 31)) * 16;
    long t = 0;
    while (__hip_atomic_load(rel, __ATOMIC_RELAXED, __HIP_MEMORY_SCOPE_AGENT) < (unsigned)phase) {
      __builtin_amdgcn_s_sleep(2);
      if (++t > 30000000L) break;  // safety valve
    }
  }
  __syncthreads();
}

// Split-K GEMV phase. All x staging loads are agent-coherent (cheap: <=128/block).
// XMODE: 0 concat(xA,xB @ splitPt) | 1 xA only | 2 concat(xA, xBias + xB)
template <int CHUNK, int XMODE, typename WT, int CONV, int TPB>
__device__ __forceinline__ void gemv_phase(
    int bid, int G,
    const float* xA, const float* xB, int splitPt, const float* xBias,
    const WT* __restrict__ W, float* __restrict__ y, int N,
    u16* convDst, float* shx, float4* red)
{
  constexpr int NSUB = TPB / 64;
  constexpr int LEN  = CHUNK / NSUB;
  const int tid = threadIdx.x, lane = tid & 63, tsub = tid >> 6;
  const int g = bid % G, s = bid / G;
  const int base = s * CHUNK;
  for (int idx = tid; idx < CHUNK; idx += TPB) {
    const int i = base + idx;
    float v;
    if (XMODE == 0)      v = (i < splitPt) ? coh_f(xA + i) : coh_f(xB + (i - splitPt));
    else if (XMODE == 1) v = coh_f(xA + i);
    else                 v = (i < splitPt) ? coh_f(xA + i)
                                           : (xBias[i - splitPt] + coh_f(xB + (i - splitPt)));
    shx[idx] = v;
  }
  __syncthreads();
  const int j = (g << 8) + (lane << 2);
  const WT* Wp = W + (size_t)(base + tsub * LEN) * N + j;
  float ax = 0.f, ay = 0.f, az = 0.f, aw = 0.f;
#pragma unroll
  for (int t = 0; t < LEN; ++t) {
    const float xi = shx[tsub * LEN + t];
    float w[4];
    if constexpr (CONV) {
      const f4v a = __builtin_nontemporal_load(
          reinterpret_cast<const f4v*>(reinterpret_cast<const float*>(Wp) + (size_t)t * N));
      w[0] = a.x; w[1] = a.y; w[2] = a.z; w[3] = a.w;
      uint2 o; o.x = pk2(w[0], w[1]); o.y = pk2(w[2], w[3]);
      *reinterpret_cast<uint2*>(convDst + (size_t)(base + tsub * LEN + t) * N + j) = o;
    } else {
      W4<WT>::load(Wp + (size_t)t * N, w);
    }
    ax = fmaf(xi, w[0], ax); ay = fmaf(xi, w[1], ay);
    az = fmaf(xi, w[2], az); aw = fmaf(xi, w[3], aw);
  }
  red[tid] = make_float4(ax, ay, az, aw);
  __syncthreads();
  if (tsub == 0) {
    float4 a = red[tid];
#pragma unroll
    for (int q = 1; q < NSUB; ++q) {
      const float4 b = red[tid + q * 64];
      a.x += b.x; a.y += b.y; a.z += b.z; a.w += b.w;
    }
    atomicAdd(&y[j + 0], a.x);
    atomicAdd(&y[j + 1], a.y);
    atomicAdd(&y[j + 2], a.z);
    atomicAdd(&y[j + 3], a.w);
  }
}

// Expert GEMV + fused LSTM, TPB=512.
template <typename WT, int CONV>
__device__ void expert_phase(const P& p, float* nb, const float* c_in, const float* gt,
                             u16* convDst, float* shx, float4* red)
{
  const int tid = threadIdx.x, lane = tid & 63, w = tid >> 6;
  const int g = blockIdx.x & 31, s = blockIdx.x >> 5;
  const int i0 = s * 128;
  if (tid < 128) {
    const int i = i0 + tid;
    const float gi = p.b_lstm[i]         + coh_f(gt + i)         + coh_f(nb + GAC + i);
    const float gf = p.b_lstm[H + i]     + coh_f(gt + H + i)     + coh_f(nb + GAC + H + i);
    const float gg = p.b_lstm[2 * H + i] + coh_f(gt + 2 * H + i) + coh_f(nb + GAC + 2 * H + i);
    const float go = p.b_lstm[3 * H + i] + coh_f(gt + 3 * H + i) + coh_f(nb + GAC + 3 * H + i);
    const float c2 = sigm(gf) * coh_f(c_in + i) + sigm(gi) * tanhf(gg);
    const float h2 = sigm(go) * tanhf(c2);
    shx[tid] = h2;
    if (g == 0) { coh_st(nb + SO + i, h2); coh_st(nb + CS + i, c2); }
  }
  __syncthreads();
  const int j = (g << 8) + (lane << 2);
  const int e = j >> 11, k = j & (H - 1);
  const size_t tileOff = ((size_t)e << 22) + (size_t)(i0 + w * 16) * H + k;
  const WT* Wp = selEx<WT>(p) + tileOff;
  float ax = 0.f, ay = 0.f, az = 0.f, aw = 0.f;
#pragma unroll
  for (int t = 0; t < 16; ++t) {
    const float xi = shx[w * 16 + t];
    float wv[4];
    if constexpr (CONV) {
      const f4v a = __builtin_nontemporal_load(
          reinterpret_cast<const f4v*>(reinterpret_cast<const float*>(Wp) + (size_t)t * H));
      wv[0] = a.x; wv[1] = a.y; wv[2] = a.z; wv[3] = a.w;
      uint2 o; o.x = pk2(wv[0], wv[1]); o.y = pk2(wv[2], wv[3]);
      *reinterpret_cast<uint2*>(convDst + tileOff + (size_t)t * H) = o;
    } else {
      W4<WT>::load(Wp + (size_t)t * H, wv);
    }
    ax = fmaf(xi, wv[0], ax); ay = fmaf(xi, wv[1], ay);
    az = fmaf(xi, wv[2], az); aw = fmaf(xi, wv[3], aw);
  }
  red[tid] = make_float4(ax, ay, az, aw);
  __syncthreads();
  if (w == 0) {
    float4 a = red[tid];
#pragma unroll
    for (int q = 1; q < 8; ++q) {
      const float4 b = red[tid + q * 64];
      a.x += b.x; a.y += b.y; a.z += b.z; a.w += b.w;
    }
    atomicAdd(&nb[EO + j + 0], a.x);
    atomicAdd(&nb[EO + j + 1], a.y);
    atomicAdd(&nb[EO + j + 2], a.z);
    atomicAdd(&nb[EO + j + 3], a.w);
  }
}

// Node phases P0..P3 with running phase counter.
template <typename WT, int CONV>
__device__ __forceinline__ void node_body(const P& p, float* nb,
                                          const float* hv, const float* cv,
                                          unsigned* ctr, int& ph,
                                          float* shx, float4* red)
{
  gemv_phase<32, 1, WT, CONV, 512>(blockIdx.x, 8, hv, nullptr, 0, nullptr,
                                   selWv<WT>(p), nb + THV, H, p.mWv, shx, red);
  resbar(ctr, ++ph);
  gemv_phase<32, 1, WT, CONV, 512>(blockIdx.x, 8, nb + THV, nullptr, 0, nullptr,
                                   selWo<WT>(p), nb + ATT, H, p.mWo, shx, red);
  resbar(ctr, ++ph);
  gemv_phase<128, 1, WT, CONV, 512>(blockIdx.x, 32, nb + ATT, nullptr, 0, nullptr,
                                    selWhh<WT>(p), nb + GAC, 4 * H, p.mWhh, shx, red);
  resbar(ctr, ++ph);
  expert_phase<WT, CONV>(p, nb, cv, p.ws + GT, p.mEx, shx, red);
  resbar(ctr, ++ph);
}

// Fin GEMVs (ram then ag) with running phase counter.
template <typename WT, int CONV>
__device__ __forceinline__ void fin_body(const P& p, float* fb,
                                         const float* aggv, const float* phpv, const float* hnv,
                                         unsigned* ctr, int& ph,
                                         float* shx, float4* red)
{
  gemv_phase<64, 0, WT, CONV, 512>(blockIdx.x, 8, aggv, phpv, H, nullptr,
                                   selRam<WT>(p), fb + ANC, H, p.mRam, shx, red);
  resbar(ctr, ++ph);
  gemv_phase<64, 2, WT, CONV, 512>(blockIdx.x, 8, hnv, fb + ANC, H, p.ram_b,
                                   selAg<WT>(p), fb + GCC, H, p.mAg, shx, red);
  resbar(ctr, ++ph);
}

// Combine phase: blocks 0..7, TPB=512. Leaf writes coherent (same-kernel consumers).
__device__ void combine_phase(const P& p, float* nb, float* dla, int leaf, float damping,
                              const float* php, float* hn, float* agg, float4* red)
{
  const int tid = threadIdx.x;
  float r0 = 0.f, r1 = 0.f, r2 = 0.f, r3 = 0.f;
  for (int i = tid; i < H; i += 512) {
    const float hh = coh_f(nb + SO + i);
    const float4 rw = *reinterpret_cast<const float4*>(p.router_w + i * 4);
    r0 = fmaf(hh, rw.x, r0); r1 = fmaf(hh, rw.y, r1);
    r2 = fmaf(hh, rw.z, r2); r3 = fmaf(hh, rw.w, r3);
  }
  red[tid] = make_float4(r0, r1, r2, r3);
  __syncthreads();
  for (int off = 256; off > 0; off >>= 1) {
    if (tid < off) {
      const float4 b = red[tid + off];
      red[tid].x += b.x; red[tid].y += b.y; red[tid].z += b.z; red[tid].w += b.w;
    }
    __syncthreads();
  }
  const float4 L = red[0];
  __syncthreads();
  const float l0 = L.x + p.router_b[0], l1 = L.y + p.router_b[1];
  const float l2 = L.z + p.router_b[2], l3 = L.w + p.router_b[3];
  const float m = fmaxf(fmaxf(l0, l1), fmaxf(l2, l3));
  const float e0 = expf(l0 - m), e1 = expf(l1 - m), e2 = expf(l2 - m), e3 = expf(l3 - m);
  const float inv = 1.f / (e0 + e1 + e2 + e3);
  const float q0 = e0 * inv, q1 = e1 * inv, q2 = e2 * inv, q3 = e3 * inv;
  const int jj = blockIdx.x * 256 + (tid & 255);
  float v = 0.f;
  if (tid < 256) {
    v = q0 * (p.expert_b[jj]         + coh_f(nb + EO + jj))
      + q1 * (p.expert_b[H + jj]     + coh_f(nb + EO + H + jj))
      + q2 * (p.expert_b[2 * H + jj] + coh_f(nb + EO + 2 * H + jj))
      + q3 * (p.expert_b[3 * H + jj] + coh_f(nb + EO + 3 * H + jj));
  }
  if (leaf) {
    if (tid < 256) {
      const float h0v = coh_f(php + jj);
      const float hnv = h0v + damping * (v - h0v);
      coh_st(hn + jj, hnv);
      coh_st(agg + jj, h0v - 0.5f * hnv);
    }
  } else {
    if (tid < 256) coh_st(nb + HP + jj, v);
    red[tid] = (tid < 256)
        ? make_float4(v * p.dr_w[jj * 3 + 0], v * p.dr_w[jj * 3 + 1], v * p.dr_w[jj * 3 + 2], 0.f)
        : make_float4(0.f, 0.f, 0.f, 0.f);
    __syncthreads();
    for (int off = 256; off > 0; off >>= 1) {
      if (tid < off) {
        const float4 b = red[tid + off];
        red[tid].x += b.x; red[tid].y += b.y; red[tid].z += b.z;
      }
      __syncthreads();
    }
    if (tid == 0) {
      atomicAdd(&dla[0], red[0].x);
      atomicAdd(&dla[1], red[0].y);
      atomicAdd(&dla[2], red[0].z);
    }
  }
}

// ---- tails (blocks 0..7, tid<256 active; no __syncthreads inside) ----
__device__ void tail_fsel(const P& p, float* ws) {
  if (threadIdx.x >= 256) return;
  if (dsteps(ws + DL, p.dr_b, 2) < 1) return;
  const bool deep = dsteps(ws + DL + 4, p.dr_b, 1) >= 1;
  const int jj = blockIdx.x * 256 + threadIdx.x;
  const float* n1 = ws + NODE + 1 * NODESZ;
  const float* n2 = ws + NODE + 2 * NODESZ;
  const float* fb = ws + FIN;
  float rh, rf, rc;
  if (deep) {
    const float gacc = p.ag_b[jj] + coh_f(fb + GCC + jj);
    const float anc  = p.ram_b[jj] + coh_f(fb + ANC + jj);
    const float g = sigm(gacc);
    rh = g * anc + (1.f - g) * coh_f(fb + HNo + jj);
    rf = coh_f(n2 + SO + jj); rc = coh_f(n2 + CS + jj);
  } else {
    rh = coh_f(n1 + HP + jj); rf = coh_f(n1 + SO + jj); rc = coh_f(n1 + CS + jj);
  }
  coh_st(ws + RH1 + jj, rh); coh_st(ws + RF1 + jj, rf); coh_st(ws + RC1 + jj, rc);
}

__device__ void tail1(const P& p, float* ws) {
  if (threadIdx.x >= 256) return;
  const int s0 = dsteps(ws + DL, p.dr_b, 2);
  if (s0 < 1) return;
  const int jj = blockIdx.x * 256 + threadIdx.x;
  const float* n0 = ws + NODE;
  const float* n3 = ws + NODE + 3 * NODESZ;
  const float* n4 = ws + NODE + 4 * NODESZ;
  const float* fb3 = ws + FIN + FINSZ;
  float* fb0 = ws + FIN + 2 * FINSZ;
  const float r1 = coh_f(ws + RH1 + jj);
  float rh3 = 0.f, rf3 = 0.f, rc3 = 0.f;
  if (s0 >= 2) {
    if (dsteps(ws + DL + 8, p.dr_b, 1) >= 1) {
      const float gacc = p.ag_b[jj] + coh_f(fb3 + GCC + jj);
      const float anc  = p.ram_b[jj] + coh_f(fb3 + ANC + jj);
      const float g = sigm(gacc);
      rh3 = g * anc + (1.f - g) * coh_f(fb3 + HNo + jj);
      rf3 = coh_f(n4 + SO + jj); rc3 = coh_f(n4 + CS + jj);
    } else {
      rh3 = coh_f(n3 + HP + jj); rf3 = coh_f(n3 + SO + jj); rc3 = coh_f(n3 + CS + jj);
    }
  }
  float ag = coh_f(n0 + HP + jj) - 0.5f * r1;
  float hc, oF, oC;
  if (s0 >= 2) { ag += (1.f / 3.f) * rh3; hc = rh3; oF = rf3; oC = rc3; }
  else { hc = r1; oF = coh_f(ws + RF1 + jj); oC = coh_f(ws + RC1 + jj); }
  coh_st(fb0 + AGGo + jj, ag); coh_st(fb0 + HNo + jj, hc);
  p.out[jj] = oF; p.out[2 * H + jj] = oC;
}

__device__ void tail2(const P& p, float* ws) {
  if (threadIdx.x >= 256) return;
  const int s0 = dsteps(ws + DL, p.dr_b, 2);
  const int jj = blockIdx.x * 256 + threadIdx.x;
  const float* n0 = ws + NODE;
  const float* fb0 = ws + FIN + 2 * FINSZ;
  if (s0 == 0) {
    p.out[jj] = coh_f(n0 + SO + jj);
    p.out[H + jj] = coh_f(n0 + HP + jj);
    p.out[2 * H + jj] = coh_f(n0 + CS + jj);
  } else {
    const float gacc = p.ag_b[jj] + coh_f(fb0 + GCC + jj);
    const float anc  = p.ram_b[jj] + coh_f(fb0 + ANC + jj);
    const float g = sigm(gacc);
    p.out[H + jj] = g * anc + (1.f - g) * coh_f(fb0 + HNo + jj);
  }
}

// ---- kernels ----
__global__ void __launch_bounds__(256) k_zero(P p) {
  float* ws = p.ws;
  const int gtid = blockIdx.x * 256 + threadIdx.x;
  const int gsz = gridDim.x * 256;
  unsigned* u = (unsigned*)ws;
  for (int i = gtid; i < CTRU; i += gsz) u[i] = 0u;
  if (gtid < 12) ws[DL + gtid] = 0.f;
  for (int i = gtid; i < 8192; i += gsz) ws[GT + i] = 0.f;
}

__global__ void __launch_bounds__(256) k_prep(P p) {
  float* ws = p.ws;
  __shared__ float shx[128];
  __shared__ float4 red[256];
  const size_t gtid = (size_t)blockIdx.x * 256 + threadIdx.x;
  const size_t nthr = (size_t)PREP_NB * 256;
  for (size_t i = gtid; i < (size_t)ZTOT; i += nthr) {
    if (i < 5 * 20480) {
      const int n = (int)(i / 20480), off = (int)(i % 20480);
      ws[NODE + n * NODESZ + off] = 0.f;
    } else {
      const int j = (int)(i - 5 * 20480);
      ws[FIN + (j >> 12) * FINSZ + (j & 4095)] = 0.f;
    }
  }
  gemv_phase<32, 0, float, 0, 256>(blockIdx.x, 32, p.x, p.x, 1 << 30, nullptr,
                                   p.Wih, ws + GT, 4 * H, nullptr, shx, red);
}

// Standalone node (N0 / N1 / N3): phases + combine(non-leaf).
template <typename WT, int CONV>
__global__ void __launch_bounds__(512, 2) k_node(
    P p, int nodeIdx, int ctrIdx, int predCode,
    const float* hv, const float* cv, float* dla)
{
  float* ws = p.ws;
  if (!pred(ws, p.dr_b, predCode)) return;
  __shared__ float shx[128];
  __shared__ float4 red[512];
  float* nb = ws + NODE + nodeIdx * NODESZ;
  unsigned* ctr = (unsigned*)ws + ctrIdx * 2048;
  int ph = 0;
  node_body<WT, CONV>(p, nb, hv, cv, ctr, ph, shx, red);
  if (blockIdx.x >= 8) return;
  combine_phase(p, nb, dla, 0, 0.f, nullptr, nullptr, nullptr, red);
}

// Fused [N2 + fin0 + fsel].
template <typename WT, typename WTF, int CONVF>
__global__ void __launch_bounds__(512, 2) k_n2fin(P p) {
  float* ws = p.ws;
  if (!pred(ws, p.dr_b, 1)) return;   // s0 >= 1 required for everything here
  __shared__ float shx[128];
  __shared__ float4 red[512];
  float* nb  = ws + NODE + 2 * NODESZ;
  float* n1  = ws + NODE + 1 * NODESZ;
  float* fb1 = ws + FIN;
  unsigned* ctr = (unsigned*)ws + 2 * 2048;
  int ph = 0;
  if (pred(ws, p.dr_b, 2)) {          // s1 >= 1: run N2 leaf
    node_body<WT, 0>(p, nb, n1 + HP, n1 + CS, ctr, ph, shx, red);
    if (blockIdx.x < 8)
      combine_phase(p, nb, nullptr, 1, 0.25f, n1 + HP, fb1 + HNo, fb1 + AGGo, red);
    resbar(ctr, ++ph);
  }
  // fin0 GEMVs run whenever s0>=1 (CONVF builds ram/ag mirror for later fins;
  // garbage-in when s1==0 is never read -- tail takes the !deep path).
  fin_body<WTF, CONVF>(p, fb1, fb1 + AGGo, n1 + HP, fb1 + HNo, ctr, ph, shx, red);
  if (blockIdx.x < 8) tail_fsel(p, ws);
}

// Fused [N4 + fin1 + tail1 + fin2 + tail2]. Launched unconditionally.
template <typename WT, typename WTF>
__global__ void __launch_bounds__(512, 2) k_n4fin(P p) {
  float* ws = p.ws;
  __shared__ float shx[128];
  __shared__ float4 red[512];
  float* nb  = ws + NODE + 4 * NODESZ;
  float* n3  = ws + NODE + 3 * NODESZ;
  float* n0  = ws + NODE;
  float* fb3 = ws + FIN + FINSZ;
  float* fb0 = ws + FIN + 2 * FINSZ;
  unsigned* ctr = (unsigned*)ws + 5 * 2048;
  int ph = 0;
  const int s0v = dsteps(ws + DL, p.dr_b, 2);
  if (s0v >= 2 && dsteps(ws + DL + 8, p.dr_b, 1) >= 1) {   // N4 + fin1
    node_body<WT, 0>(p, nb, n3 + HP, n3 + CS, ctr, ph, shx, red);
    if (blockIdx.x < 8)
      combine_phase(p, nb, nullptr, 1, 0.25f, n3 + HP, fb3 + HNo, fb3 + AGGo, red);
    resbar(ctr, ++ph);
    fin_body<WTF, 0>(p, fb3, fb3 + AGGo, n3 + HP, fb3 + HNo, ctr, ph, shx, red);
  }
  if (s0v >= 1) {
    if (blockIdx.x < 8) tail1(p, ws);
    resbar(ctr, ++ph);
    fin_body<WTF, 0>(p, fb0, fb0 + AGGo, n0 + HP, fb0 + HNo, ctr, ph, shx, red);
  }
  if (blockIdx.x < 8) tail2(p, ws);
}

extern "C" void kernel_launch(void* const* d_in, const int* in_sizes, int n_in,
                              void* d_out, int out_size, void* d_ws, size_t ws_size,
                              hipStream_t stream) {
  P p;
  p.x = (const float*)d_in[0];  p.h0 = (const float*)d_in[1];  p.c0 = (const float*)d_in[2];
  p.Wv = (const float*)d_in[5]; p.Wo = (const float*)d_in[6];
  p.Wih = (const float*)d_in[7]; p.Whh = (const float*)d_in[8];
  p.b_lstm = (const float*)d_in[9];
  p.router_w = (const float*)d_in[10]; p.router_b = (const float*)d_in[11];
  p.expert_w = (const float*)d_in[12]; p.expert_b = (const float*)d_in[13];
  p.dr_w = (const float*)d_in[14]; p.dr_b = (const float*)d_in[15];
  p.ram_w = (const float*)d_in[16]; p.ram_b = (const float*)d_in[17];
  p.ag_w = (const float*)d_in[18]; p.ag_b = (const float*)d_in[19];
  p.out = (float*)d_out;
  p.ws = (float*)d_ws;

  const bool useBf    = ws_size >= BF_BYTE_OFF + BF_NODE * 2 + 1024;
  const bool useBfFin = ws_size >= BF_BYTE_OFF + BF_ALL * 2 + 1024;
  u16* bf = (u16*)((char*)d_ws + BF_BYTE_OFF);
  p.bWv = bf;        p.bWo = bf + oWo;   p.bWhh = bf + oWhh;
  p.bEx = bf + oEx;  p.bRam = bf + oRam; p.bAg  = bf + oAg;
  p.mWv = bf;        p.mWo = bf + oWo;   p.mWhh = bf + oWhh;
  p.mEx = bf + oEx;  p.mRam = bf + oRam; p.mAg  = bf + oAg;

  float* ws = p.ws;
  auto nb = [&](int n) { return ws + NODE + n * NODESZ; };

  k_zero<<<16, 256, 0, stream>>>(p);
  k_prep<<<PREP_NB, 256, 0, stream>>>(p);

  // N0 (convert-while-compute when ws fits)
  if (useBf)
    k_node<float, 1><<<NB, 512, 0, stream>>>(p, 0, 0, 0, p.h0, p.c0, ws + DL);
  else
    k_node<float, 0><<<NB, 512, 0, stream>>>(p, 0, 0, 0, p.h0, p.c0, ws + DL);

  // N1 (s0>=1)
  if (useBf)
    k_node<u16, 0><<<NB, 512, 0, stream>>>(p, 1, 1, 1, nb(0) + HP, nb(0) + CS, ws + DL + 4);
  else
    k_node<float, 0><<<NB, 512, 0, stream>>>(p, 1, 1, 1, nb(0) + HP, nb(0) + CS, ws + DL + 4);

  // [N2 + fin0 + fsel]
  if (useBf && useBfFin)
    k_n2fin<u16, float, 1><<<NB, 512, 0, stream>>>(p);
  else if (useBf)
    k_n2fin<u16, float, 0><<<NB, 512, 0, stream>>>(p);
  else
    k_n2fin<float, float, 0><<<NB, 512, 0, stream>>>(p);

  // N3 (s0>=2)
  if (useBf)
    k_node<u16, 0><<<NB, 512, 0, stream>>>(p, 3, 4, 3, ws + RH1, ws + RC1, ws + DL + 8);
  else
    k_node<float, 0><<<NB, 512, 0, stream>>>(p, 3, 4, 3, ws + RH1, ws + RC1, ws + DL + 8);

  // [N4 + fin1 + tail1 + fin2 + tail2]
  if (useBf && useBfFin)
    k_n4fin<u16, u16><<<NB, 512, 0, stream>>>(p);
  else if (useBf)
    k_n4fin<u16, float><<<NB, 512, 0, stream>>>(p);
  else
    k_n4fin<float, float><<<NB, 512, 0, stream>>>(p);
}

// Round 21
// 332.355 us; speedup vs baseline: 1.0717x; 1.0157x over previous
//
#include <hip/hip_runtime.h>
#include <math.h>

// FractalOpponent on MI355X, round 21.
// = R20 with full continuation-fusion: 4 launches total.
//   k_zero   : zero counters + DL + GT + node/fin accumulators (512 blocks)
//   k_n0     : [Wih GEMV | Wv | Wo | Whh | expert | combine]  (conversion fused)
//   k_n12fin : [N1 | N2 | fin0 | fsel]
//   k_n34fin : [N3 | N4 | fin1 | tail1 | fin2 | tail2]

#define H 2048
#define NB 512
typedef unsigned short u16;
typedef float f4v __attribute__((ext_vector_type(4)));

struct P {
  const float *x, *h0, *c0, *Wv, *Wo, *Wih, *Whh, *b_lstm, *router_w, *router_b,
              *expert_w, *expert_b, *dr_w, *dr_b, *ram_w, *ram_b, *ag_w, *ag_b;
  const u16 *bWv, *bWo, *bWhh, *bEx, *bRam, *bAg;
  u16 *mWv, *mWo, *mWhh, *mEx, *mRam, *mAg;
  float* out;
  float* ws;
};

// ---- ws layout (floats) ----
constexpr int CTRU   = 16384;    // 3 barrier regions x 2048 uints (zeroed fully)
constexpr int DL     = 16384;
constexpr int GT     = 16400;
constexpr int NODE   = 24592;
constexpr int NODESZ = 26624;
constexpr int THV = 0, ATT = 2048, GAC = 4096, EO = 12288, SO = 20480, CS = 22528, HP = 24576;
constexpr int FIN    = NODE + 5 * NODESZ;
constexpr int FINSZ  = 8192;
constexpr int ANC = 0, GCC = 2048, HNo = 4096, AGGo = 6144;
constexpr int RH1 = FIN + 3 * FINSZ;
constexpr int RF1 = RH1 + 2048;
constexpr int RC1 = RH1 + 4096;
constexpr int ZTOT = 5 * 20480 + 3 * 4096;
constexpr size_t BF_BYTE_OFF = 786432;
constexpr size_t oWo  = 4194304;
constexpr size_t oWhh = 8388608;
constexpr size_t oEx  = 25165824;
constexpr size_t oRam = 41943040;
constexpr size_t oAg  = 50331648;
constexpr size_t BF_NODE = 41943040;
constexpr size_t BF_ALL  = 58720256;

__device__ __forceinline__ float sigm(float v) { return 1.f / (1.f + expf(-v)); }

__device__ __forceinline__ float coh_f(const float* p) {
  return __hip_atomic_load(p, __ATOMIC_RELAXED, __HIP_MEMORY_SCOPE_AGENT);
}
__device__ __forceinline__ void coh_st(float* p, float v) {
  __hip_atomic_store(p, v, __ATOMIC_RELAXED, __HIP_MEMORY_SCOPE_AGENT);
}

__device__ __forceinline__ float bfl(unsigned u) { union { unsigned x; float f; } c; c.x = u << 16; return c.f; }
__device__ __forceinline__ float bfh(unsigned u) { union { unsigned x; float f; } c; c.x = u & 0xFFFF0000u; return c.f; }
__device__ __forceinline__ u16 f2bf(float f) {
  unsigned u = __float_as_uint(f);
  u += 0x7FFFu + ((u >> 16) & 1u);
  return (u16)(u >> 16);
}
__device__ __forceinline__ unsigned pk2(float a, float b) {
  return (unsigned)f2bf(a) | ((unsigned)f2bf(b) << 16);
}

template <typename WT> struct W4;
template <> struct W4<float> {
  static __device__ __forceinline__ void load(const float* p, float* w) {
    const float4 v = *reinterpret_cast<const float4*>(p);
    w[0] = v.x; w[1] = v.y; w[2] = v.z; w[3] = v.w;
  }
};
template <> struct W4<u16> {
  static __device__ __forceinline__ void load(const u16* p, float* w) {
    const uint2 u = *reinterpret_cast<const uint2*>(p);
    w[0] = bfl(u.x); w[1] = bfh(u.x); w[2] = bfl(u.y); w[3] = bfh(u.y);
  }
};

template <typename WT> __device__ __forceinline__ const WT* selWv(const P& p);
template <> __device__ __forceinline__ const float* selWv<float>(const P& p) { return p.Wv; }
template <> __device__ __forceinline__ const u16*   selWv<u16>(const P& p)   { return p.bWv; }
template <typename WT> __device__ __forceinline__ const WT* selWo(const P& p);
template <> __device__ __forceinline__ const float* selWo<float>(const P& p) { return p.Wo; }
template <> __device__ __forceinline__ const u16*   selWo<u16>(const P& p)   { return p.bWo; }
template <typename WT> __device__ __forceinline__ const WT* selWhh(const P& p);
template <> __device__ __forceinline__ const float* selWhh<float>(const P& p) { return p.Whh; }
template <> __device__ __forceinline__ const u16*   selWhh<u16>(const P& p)   { return p.bWhh; }
template <typename WT> __device__ __forceinline__ const WT* selEx(const P& p);
template <> __device__ __forceinline__ const float* selEx<float>(const P& p) { return p.expert_w; }
template <> __device__ __forceinline__ const u16*   selEx<u16>(const P& p)   { return p.bEx; }
template <typename WT> __device__ __forceinline__ const WT* selRam(const P& p);
template <> __device__ __forceinline__ const float* selRam<float>(const P& p) { return p.ram_w; }
template <> __device__ __forceinline__ const u16*   selRam<u16>(const P& p)   { return p.bRam; }
template <typename WT> __device__ __forceinline__ const WT* selAg(const P& p);
template <> __device__ __forceinline__ const float* selAg<float>(const P& p) { return p.ag_w; }
template <> __device__ __forceinline__ const u16*   selAg<u16>(const P& p)   { return p.bAg; }

__device__ __forceinline__ int dsteps(const float* dla, const float* drb, int mx) {
  const float l0 = coh_f(dla + 0) + drb[0];
  const float l1 = coh_f(dla + 1) + drb[1];
  const float l2 = coh_f(dla + 2) + drb[2];
  int ch = 0; float bv = l0;
  if (l1 > bv) { bv = l1; ch = 1; }
  if (l2 > bv) { bv = l2; ch = 2; }
  return ch < mx ? ch : mx;
}

// Tree barrier, 512 blocks, region = 2048 uints.
__device__ __forceinline__ void resbar(unsigned* ctr, int phase) {
  asm volatile("s_waitcnt vmcnt(0)" ::: "memory");
  __syncthreads();
  __shared__ int lastB;
  if (threadIdx.x == 0) {
    lastB = 0;
    unsigned* line = ctr + (blockIdx.x & 31) * 16;
    const unsigned prev = __hip_atomic_fetch_add(line, 1u, __ATOMIC_RELAXED, __HIP_MEMORY_SCOPE_AGENT);
    if (prev == (unsigned)(16 * phase) - 1u) {
      const unsigned m = __hip_atomic_fetch_add(ctr + 512, 1u, __ATOMIC_RELAXED, __HIP_MEMORY_SCOPE_AGENT);
      if (m == (unsigned)(32 * phase) - 1u) lastB = 1;
    }
  }
  __syncthreads();
  if (lastB) {
    if (threadIdx.x < 32)
      __hip_atomic_store(ctr + (40 + threadIdx.x) * 16, (unsigned)phase,
                         __ATOMIC_RELAXED, __HIP_MEMORY_SCOPE_AGENT);
  } else if (threadIdx.x == 0) {
    const unsigned* rel = ctr + (40 + (blockIdx.x & 31)) * 16;
    long t = 0;
    while (__hip_atomic_load(rel, __ATOMIC_RELAXED, __HIP_MEMORY_SCOPE_AGENT) < (unsigned)phase) {
      __builtin_amdgcn_s_sleep(2);
      if (++t > 30000000L) break;  // safety valve
    }
  }
  __syncthreads();
}

// Split-K GEMV phase (coherent staging loads).
// XMODE: 0 concat(xA,xB @ splitPt) | 1 xA only | 2 concat(xA, xBias + xB)
template <int CHUNK, int XMODE, typename WT, int CONV, int TPB>
__device__ __forceinline__ void gemv_phase(
    int bid, int G,
    const float* xA, const float* xB, int splitPt, const float* xBias,
    const WT* __restrict__ W, float* __restrict__ y, int N,
    u16* convDst, float* shx, float4* red)
{
  constexpr int NSUB = TPB / 64;
  constexpr int LEN  = CHUNK / NSUB;
  const int tid = threadIdx.x, lane = tid & 63, tsub = tid >> 6;
  const int g = bid % G, s = bid / G;
  const int base = s * CHUNK;
  for (int idx = tid; idx < CHUNK; idx += TPB) {
    const int i = base + idx;
    float v;
    if (XMODE == 0)      v = (i < splitPt) ? coh_f(xA + i) : coh_f(xB + (i - splitPt));
    else if (XMODE == 1) v = coh_f(xA + i);
    else                 v = (i < splitPt) ? coh_f(xA + i)
                                           : (xBias[i - splitPt] + coh_f(xB + (i - splitPt)));
    shx[idx] = v;
  }
  __syncthreads();
  const int j = (g << 8) + (lane << 2);
  const WT* Wp = W + (size_t)(base + tsub * LEN) * N + j;
  float ax = 0.f, ay = 0.f, az = 0.f, aw = 0.f;
#pragma unroll
  for (int t = 0; t < LEN; ++t) {
    const float xi = shx[tsub * LEN + t];
    float w[4];
    if constexpr (CONV) {
      const f4v a = __builtin_nontemporal_load(
          reinterpret_cast<const f4v*>(reinterpret_cast<const float*>(Wp) + (size_t)t * N));
      w[0] = a.x; w[1] = a.y; w[2] = a.z; w[3] = a.w;
      uint2 o; o.x = pk2(w[0], w[1]); o.y = pk2(w[2], w[3]);
      *reinterpret_cast<uint2*>(convDst + (size_t)(base + tsub * LEN + t) * N + j) = o;
    } else {
      W4<WT>::load(Wp + (size_t)t * N, w);
    }
    ax = fmaf(xi, w[0], ax); ay = fmaf(xi, w[1], ay);
    az = fmaf(xi, w[2], az); aw = fmaf(xi, w[3], aw);
  }
  red[tid] = make_float4(ax, ay, az, aw);
  __syncthreads();
  if (tsub == 0) {
    float4 a = red[tid];
#pragma unroll
    for (int q = 1; q < NSUB; ++q) {
      const float4 b = red[tid + q * 64];
      a.x += b.x; a.y += b.y; a.z += b.z; a.w += b.w;
    }
    atomicAdd(&y[j + 0], a.x);
    atomicAdd(&y[j + 1], a.y);
    atomicAdd(&y[j + 2], a.z);
    atomicAdd(&y[j + 3], a.w);
  }
}

// Expert GEMV + fused LSTM, TPB=512.
template <typename WT, int CONV>
__device__ void expert_phase(const P& p, float* nb, const float* c_in, const float* gt,
                             u16* convDst, float* shx, float4* red)
{
  const int tid = threadIdx.x, lane = tid & 63, w = tid >> 6;
  const int g = blockIdx.x & 31, s = blockIdx.x >> 5;
  const int i0 = s * 128;
  if (tid < 128) {
    const int i = i0 + tid;
    const float gi = p.b_lstm[i]         + coh_f(gt + i)         + coh_f(nb + GAC + i);
    const float gf = p.b_lstm[H + i]     + coh_f(gt + H + i)     + coh_f(nb + GAC + H + i);
    const float gg = p.b_lstm[2 * H + i] + coh_f(gt + 2 * H + i) + coh_f(nb + GAC + 2 * H + i);
    const float go = p.b_lstm[3 * H + i] + coh_f(gt + 3 * H + i) + coh_f(nb + GAC + 3 * H + i);
    const float c2 = sigm(gf) * coh_f(c_in + i) + sigm(gi) * tanhf(gg);
    const float h2 = sigm(go) * tanhf(c2);
    shx[tid] = h2;
    if (g == 0) { coh_st(nb + SO + i, h2); coh_st(nb + CS + i, c2); }
  }
  __syncthreads();
  const int j = (g << 8) + (lane << 2);
  const int e = j >> 11, k = j & (H - 1);
  const size_t tileOff = ((size_t)e << 22) + (size_t)(i0 + w * 16) * H + k;
  const WT* Wp = selEx<WT>(p) + tileOff;
  float ax = 0.f, ay = 0.f, az = 0.f, aw = 0.f;
#pragma unroll
  for (int t = 0; t < 16; ++t) {
    const float xi = shx[w * 16 + t];
    float wv[4];
    if constexpr (CONV) {
      const f4v a = __builtin_nontemporal_load(
          reinterpret_cast<const f4v*>(reinterpret_cast<const float*>(Wp) + (size_t)t * H));
      wv[0] = a.x; wv[1] = a.y; wv[2] = a.z; wv[3] = a.w;
      uint2 o; o.x = pk2(wv[0], wv[1]); o.y = pk2(wv[2], wv[3]);
      *reinterpret_cast<uint2*>(convDst + tileOff + (size_t)t * H) = o;
    } else {
      W4<WT>::load(Wp + (size_t)t * H, wv);
    }
    ax = fmaf(xi, wv[0], ax); ay = fmaf(xi, wv[1], ay);
    az = fmaf(xi, wv[2], az); aw = fmaf(xi, wv[3], aw);
  }
  red[tid] = make_float4(ax, ay, az, aw);
  __syncthreads();
  if (w == 0) {
    float4 a = red[tid];
#pragma unroll
    for (int q = 1; q < 8; ++q) {
      const float4 b = red[tid + q * 64];
      a.x += b.x; a.y += b.y; a.z += b.z; a.w += b.w;
    }
    atomicAdd(&nb[EO + j + 0], a.x);
    atomicAdd(&nb[EO + j + 1], a.y);
    atomicAdd(&nb[EO + j + 2], a.z);
    atomicAdd(&nb[EO + j + 3], a.w);
  }
}

// Node phases P0..P3 with running phase counter.
template <typename WT, int CONV>
__device__ __forceinline__ void node_body(const P& p, float* nb,
                                          const float* hv, const float* cv,
                                          unsigned* ctr, int& ph,
                                          float* shx, float4* red)
{
  gemv_phase<32, 1, WT, CONV, 512>(blockIdx.x, 8, hv, nullptr, 0, nullptr,
                                   selWv<WT>(p), nb + THV, H, p.mWv, shx, red);
  resbar(ctr, ++ph);
  gemv_phase<32, 1, WT, CONV, 512>(blockIdx.x, 8, nb + THV, nullptr, 0, nullptr,
                                   selWo<WT>(p), nb + ATT, H, p.mWo, shx, red);
  resbar(ctr, ++ph);
  gemv_phase<128, 1, WT, CONV, 512>(blockIdx.x, 32, nb + ATT, nullptr, 0, nullptr,
                                    selWhh<WT>(p), nb + GAC, 4 * H, p.mWhh, shx, red);
  resbar(ctr, ++ph);
  expert_phase<WT, CONV>(p, nb, cv, p.ws + GT, p.mEx, shx, red);
  resbar(ctr, ++ph);
}

// Fin GEMVs with running phase counter.
template <typename WT, int CONV>
__device__ __forceinline__ void fin_body(const P& p, float* fb,
                                         const float* aggv, const float* phpv, const float* hnv,
                                         unsigned* ctr, int& ph,
                                         float* shx, float4* red)
{
  gemv_phase<64, 0, WT, CONV, 512>(blockIdx.x, 8, aggv, phpv, H, nullptr,
                                   selRam<WT>(p), fb + ANC, H, p.mRam, shx, red);
  resbar(ctr, ++ph);
  gemv_phase<64, 2, WT, CONV, 512>(blockIdx.x, 8, hnv, fb + ANC, H, p.ram_b,
                                   selAg<WT>(p), fb + GCC, H, p.mAg, shx, red);
  resbar(ctr, ++ph);
}

// Combine phase: blocks 0..7, TPB=512.
__device__ void combine_phase(const P& p, float* nb, float* dla, int leaf, float damping,
                              const float* php, float* hn, float* agg, float4* red)
{
  const int tid = threadIdx.x;
  float r0 = 0.f, r1 = 0.f, r2 = 0.f, r3 = 0.f;
  for (int i = tid; i < H; i += 512) {
    const float hh = coh_f(nb + SO + i);
    const float4 rw = *reinterpret_cast<const float4*>(p.router_w + i * 4);
    r0 = fmaf(hh, rw.x, r0); r1 = fmaf(hh, rw.y, r1);
    r2 = fmaf(hh, rw.z, r2); r3 = fmaf(hh, rw.w, r3);
  }
  red[tid] = make_float4(r0, r1, r2, r3);
  __syncthreads();
  for (int off = 256; off > 0; off >>= 1) {
    if (tid < off) {
      const float4 b = red[tid + off];
      red[tid].x += b.x; red[tid].y += b.y; red[tid].z += b.z; red[tid].w += b.w;
    }
    __syncthreads();
  }
  const float4 L = red[0];
  __syncthreads();
  const float l0 = L.x + p.router_b[0], l1 = L.y + p.router_b[1];
  const float l2 = L.z + p.router_b[2], l3 = L.w + p.router_b[3];
  const float m = fmaxf(fmaxf(l0, l1), fmaxf(l2, l3));
  const float e0 = expf(l0 - m), e1 = expf(l1 - m), e2 = expf(l2 - m), e3 = expf(l3 - m);
  const float inv = 1.f / (e0 + e1 + e2 + e3);
  const float q0 = e0 * inv, q1 = e1 * inv, q2 = e2 * inv, q3 = e3 * inv;
  const int jj = blockIdx.x * 256 + (tid & 255);
  float v = 0.f;
  if (tid < 256) {
    v = q0 * (p.expert_b[jj]         + coh_f(nb + EO + jj))
      + q1 * (p.expert_b[H + jj]     + coh_f(nb + EO + H + jj))
      + q2 * (p.expert_b[2 * H + jj] + coh_f(nb + EO + 2 * H + jj))
      + q3 * (p.expert_b[3 * H + jj] + coh_f(nb + EO + 3 * H + jj));
  }
  if (leaf) {
    if (tid < 256) {
      const float h0v = coh_f(php + jj);
      const float hnv = h0v + damping * (v - h0v);
      coh_st(hn + jj, hnv);
      coh_st(agg + jj, h0v - 0.5f * hnv);
    }
  } else {
    if (tid < 256) coh_st(nb + HP + jj, v);
    red[tid] = (tid < 256)
        ? make_float4(v * p.dr_w[jj * 3 + 0], v * p.dr_w[jj * 3 + 1], v * p.dr_w[jj * 3 + 2], 0.f)
        : make_float4(0.f, 0.f, 0.f, 0.f);
    __syncthreads();
    for (int off = 256; off > 0; off >>= 1) {
      if (tid < off) {
        const float4 b = red[tid + off];
        red[tid].x += b.x; red[tid].y += b.y; red[tid].z += b.z;
      }
      __syncthreads();
    }
    if (tid == 0) {
      atomicAdd(&dla[0], red[0].x);
      atomicAdd(&dla[1], red[0].y);
      atomicAdd(&dla[2], red[0].z);
    }
  }
}

// ---- tails (blocks 0..7, tid<256 active) ----
__device__ void tail_fsel(const P& p, float* ws) {
  if (threadIdx.x >= 256) return;
  if (dsteps(ws + DL, p.dr_b, 2) < 1) return;
  const bool deep = dsteps(ws + DL + 4, p.dr_b, 1) >= 1;
  const int jj = blockIdx.x * 256 + threadIdx.x;
  const float* n1 = ws + NODE + 1 * NODESZ;
  const float* n2 = ws + NODE + 2 * NODESZ;
  const float* fb = ws + FIN;
  float rh, rf, rc;
  if (deep) {
    const float gacc = p.ag_b[jj] + coh_f(fb + GCC + jj);
    const float anc  = p.ram_b[jj] + coh_f(fb + ANC + jj);
    const float g = sigm(gacc);
    rh = g * anc + (1.f - g) * coh_f(fb + HNo + jj);
    rf = coh_f(n2 + SO + jj); rc = coh_f(n2 + CS + jj);
  } else {
    rh = coh_f(n1 + HP + jj); rf = coh_f(n1 + SO + jj); rc = coh_f(n1 + CS + jj);
  }
  coh_st(ws + RH1 + jj, rh); coh_st(ws + RF1 + jj, rf); coh_st(ws + RC1 + jj, rc);
}

__device__ void tail1(const P& p, float* ws) {
  if (threadIdx.x >= 256) return;
  const int s0 = dsteps(ws + DL, p.dr_b, 2);
  if (s0 < 1) return;
  const int jj = blockIdx.x * 256 + threadIdx.x;
  const float* n0 = ws + NODE;
  const float* n3 = ws + NODE + 3 * NODESZ;
  const float* n4 = ws + NODE + 4 * NODESZ;
  const float* fb3 = ws + FIN + FINSZ;
  float* fb0 = ws + FIN + 2 * FINSZ;
  const float r1 = coh_f(ws + RH1 + jj);
  float rh3 = 0.f, rf3 = 0.f, rc3 = 0.f;
  if (s0 >= 2) {
    if (dsteps(ws + DL + 8, p.dr_b, 1) >= 1) {
      const float gacc = p.ag_b[jj] + coh_f(fb3 + GCC + jj);
      const float anc  = p.ram_b[jj] + coh_f(fb3 + ANC + jj);
      const float g = sigm(gacc);
      rh3 = g * anc + (1.f - g) * coh_f(fb3 + HNo + jj);
      rf3 = coh_f(n4 + SO + jj); rc3 = coh_f(n4 + CS + jj);
    } else {
      rh3 = coh_f(n3 + HP + jj); rf3 = coh_f(n3 + SO + jj); rc3 = coh_f(n3 + CS + jj);
    }
  }
  float ag = coh_f(n0 + HP + jj) - 0.5f * r1;
  float hc, oF, oC;
  if (s0 >= 2) { ag += (1.f / 3.f) * rh3; hc = rh3; oF = rf3; oC = rc3; }
  else { hc = r1; oF = coh_f(ws + RF1 + jj); oC = coh_f(ws + RC1 + jj); }
  coh_st(fb0 + AGGo + jj, ag); coh_st(fb0 + HNo + jj, hc);
  p.out[jj] = oF; p.out[2 * H + jj] = oC;
}

__device__ void tail2(const P& p, float* ws) {
  if (threadIdx.x >= 256) return;
  const int s0 = dsteps(ws + DL, p.dr_b, 2);
  const int jj = blockIdx.x * 256 + threadIdx.x;
  const float* n0 = ws + NODE;
  const float* fb0 = ws + FIN + 2 * FINSZ;
  if (s0 == 0) {
    p.out[jj] = coh_f(n0 + SO + jj);
    p.out[H + jj] = coh_f(n0 + HP + jj);
    p.out[2 * H + jj] = coh_f(n0 + CS + jj);
  } else {
    const float gacc = p.ag_b[jj] + coh_f(fb0 + GCC + jj);
    const float anc  = p.ram_b[jj] + coh_f(fb0 + ANC + jj);
    const float g = sigm(gacc);
    p.out[H + jj] = g * anc + (1.f - g) * coh_f(fb0 + HNo + jj);
  }
}

// ---- kernels ----
__global__ void __launch_bounds__(256) k_zero(P p) {
  float* ws = p.ws;
  const int gtid = blockIdx.x * 256 + threadIdx.x;
  const int gsz = gridDim.x * 256;
  unsigned* u = (unsigned*)ws;
  for (int i = gtid; i < CTRU; i += gsz) u[i] = 0u;
  if (gtid < 12) ws[DL + gtid] = 0.f;
  for (int i = gtid; i < 8192; i += gsz) ws[GT + i] = 0.f;
  for (int i = gtid; i < ZTOT; i += gsz) {
    if (i < 5 * 20480) {
      const int n = i / 20480, off = i % 20480;
      ws[NODE + n * NODESZ + off] = 0.f;
    } else {
      const int j = i - 5 * 20480;
      ws[FIN + (j >> 12) * FINSZ + (j & 4095)] = 0.f;
    }
  }
}

// N0 kernel: [Wih | Wv | Wo | Whh | expert | combine].
template <int CONV>
__global__ void __launch_bounds__(512, 2) k_n0(P p) {
  float* ws = p.ws;
  __shared__ float shx[128];
  __shared__ float4 red[512];
  float* nb = ws + NODE;
  unsigned* ctr = (unsigned*)ws;     // region 0
  int ph = 0;
  // Wih GEMV (fp32, once): G=32, KS=16, CHUNK=128
  gemv_phase<128, 1, float, 0, 512>(blockIdx.x, 32, p.x, nullptr, 0, nullptr,
                                    p.Wih, ws + GT, 4 * H, nullptr, shx, red);
  resbar(ctr, ++ph);
  node_body<float, CONV>(p, nb, p.h0, p.c0, ctr, ph, shx, red);
  if (blockIdx.x >= 8) return;
  combine_phase(p, nb, ws + DL, 0, 0.f, nullptr, nullptr, nullptr, red);
}

// [N1 + N2 + fin0 + fsel]
template <typename WT, typename WTF, int CONVF>
__global__ void __launch_bounds__(512, 2) k_n12fin(P p) {
  float* ws = p.ws;
  if (dsteps(ws + DL, p.dr_b, 2) < 1) return;   // s0 >= 1 gates everything here
  __shared__ float shx[128];
  __shared__ float4 red[512];
  float* n1  = ws + NODE + 1 * NODESZ;
  float* n2  = ws + NODE + 2 * NODESZ;
  float* n0  = ws + NODE;
  float* fb1 = ws + FIN;
  unsigned* ctr = (unsigned*)ws + 1 * 2048;     // region 1
  int ph = 0;
  // N1
  node_body<WT, 0>(p, n1, n0 + HP, n0 + CS, ctr, ph, shx, red);
  if (blockIdx.x < 8)
    combine_phase(p, n1, ws + DL + 4, 0, 0.f, nullptr, nullptr, nullptr, red);
  resbar(ctr, ++ph);
  // N2 leaf (s1 >= 1)
  if (dsteps(ws + DL + 4, p.dr_b, 1) >= 1) {
    node_body<WT, 0>(p, n2, n1 + HP, n1 + CS, ctr, ph, shx, red);
    if (blockIdx.x < 8)
      combine_phase(p, n2, nullptr, 1, 0.25f, n1 + HP, fb1 + HNo, fb1 + AGGo, red);
    resbar(ctr, ++ph);
  }
  // fin0 (always when s0>=1: builds ram/ag mirror; garbage-in unread when s1==0)
  fin_body<WTF, CONVF>(p, fb1, fb1 + AGGo, n1 + HP, fb1 + HNo, ctr, ph, shx, red);
  if (blockIdx.x < 8) tail_fsel(p, ws);
}

// [N3 + N4 + fin1 + tail1 + fin2 + tail2]
template <typename WT, typename WTF>
__global__ void __launch_bounds__(512, 2) k_n34fin(P p) {
  float* ws = p.ws;
  __shared__ float shx[128];
  __shared__ float4 red[512];
  float* n3  = ws + NODE + 3 * NODESZ;
  float* n4  = ws + NODE + 4 * NODESZ;
  float* n0  = ws + NODE;
  float* fb3 = ws + FIN + FINSZ;
  float* fb0 = ws + FIN + 2 * FINSZ;
  unsigned* ctr = (unsigned*)ws + 2 * 2048;     // region 2
  int ph = 0;
  const int s0v = dsteps(ws + DL, p.dr_b, 2);
  if (s0v >= 2) {
    // N3
    node_body<WT, 0>(p, n3, ws + RH1, ws + RC1, ctr, ph, shx, red);
    if (blockIdx.x < 8)
      combine_phase(p, n3, ws + DL + 8, 0, 0.f, nullptr, nullptr, nullptr, red);
    resbar(ctr, ++ph);
    if (dsteps(ws + DL + 8, p.dr_b, 1) >= 1) {
      // N4 leaf + fin1
      node_body<WT, 0>(p, n4, n3 + HP, n3 + CS, ctr, ph, shx, red);
      if (blockIdx.x < 8)
        combine_phase(p, n4, nullptr, 1, 0.25f, n3 + HP, fb3 + HNo, fb3 + AGGo, red);
      resbar(ctr, ++ph);
      fin_body<WTF, 0>(p, fb3, fb3 + AGGo, n3 + HP, fb3 + HNo, ctr, ph, shx, red);
    }
  }
  if (s0v >= 1) {
    if (blockIdx.x < 8) tail1(p, ws);
    resbar(ctr, ++ph);
    fin_body<WTF, 0>(p, fb0, fb0 + AGGo, n0 + HP, fb0 + HNo, ctr, ph, shx, red);
  }
  if (blockIdx.x < 8) tail2(p, ws);
}

extern "C" void kernel_launch(void* const* d_in, const int* in_sizes, int n_in,
                              void* d_out, int out_size, void* d_ws, size_t ws_size,
                              hipStream_t stream) {
  P p;
  p.x = (const float*)d_in[0];  p.h0 = (const float*)d_in[1];  p.c0 = (const float*)d_in[2];
  p.Wv = (const float*)d_in[5]; p.Wo = (const float*)d_in[6];
  p.Wih = (const float*)d_in[7]; p.Whh = (const float*)d_in[8];
  p.b_lstm = (const float*)d_in[9];
  p.router_w = (const float*)d_in[10]; p.router_b = (const float*)d_in[11];
  p.expert_w = (const float*)d_in[12]; p.expert_b = (const float*)d_in[13];
  p.dr_w = (const float*)d_in[14]; p.dr_b = (const float*)d_in[15];
  p.ram_w = (const float*)d_in[16]; p.ram_b = (const float*)d_in[17];
  p.ag_w = (const float*)d_in[18]; p.ag_b = (const float*)d_in[19];
  p.out = (float*)d_out;
  p.ws = (float*)d_ws;

  const bool useBf    = ws_size >= BF_BYTE_OFF + BF_NODE * 2 + 1024;
  const bool useBfFin = ws_size >= BF_BYTE_OFF + BF_ALL * 2 + 1024;
  u16* bf = (u16*)((char*)d_ws + BF_BYTE_OFF);
  p.bWv = bf;        p.bWo = bf + oWo;   p.bWhh = bf + oWhh;
  p.bEx = bf + oEx;  p.bRam = bf + oRam; p.bAg  = bf + oAg;
  p.mWv = bf;        p.mWo = bf + oWo;   p.mWhh = bf + oWhh;
  p.mEx = bf + oEx;  p.mRam = bf + oRam; p.mAg  = bf + oAg;

  k_zero<<<512, 256, 0, stream>>>(p);

  if (useBf)
    k_n0<1><<<NB, 512, 0, stream>>>(p);
  else
    k_n0<0><<<NB, 512, 0, stream>>>(p);

  if (useBf && useBfFin)
    k_n12fin<u16, float, 1><<<NB, 512, 0, stream>>>(p);
  else if (useBf)
    k_n12fin<u16, float, 0><<<NB, 512, 0, stream>>>(p);
  else
    k_n12fin<float, float, 0><<<NB, 512, 0, stream>>>(p);

  if (useBf && useBfFin)
    k_n34fin<u16, u16><<<NB, 512, 0, stream>>>(p);
  else if (useBf)
    k_n34fin<u16, float><<<NB, 512, 0, stream>>>(p);
  else
    k_n34fin<float, float><<<NB, 512, 0, stream>>>(p);
}